// Round 10
// baseline (404.892 us; speedup 1.0000x reference)
//
#include <hip/hip_runtime.h>
#include <float.h>

typedef unsigned short u16;
typedef unsigned int u32;

// B=2, N=8192, M=4096, C=64, K=16, HID=256
__device__ __forceinline__ float bf(u16 u) { return __uint_as_float(((u32)u) << 16); }
__device__ __forceinline__ u16 f2bf(float v) {
    u32 x = __float_as_uint(v);
    u32 r = x + 0x7fffu + ((x >> 16) & 1u);
    return (u16)(r >> 16);
}
// Dtype probe on EVEN u16 positions of a large ~N(0,1) buffer (pcl_noise).
__device__ __forceinline__ int detect_f32(const void* probe) {
    const u16* u = (const u16*)probe;
    u16 v = u[(threadIdx.x & 63) * 2];
    int e = (int)((v >> 7) & 0xFF);
    int moderate = (e >= 100) && (e <= 140);
    return __popcll(__ballot(moderate)) < 48;   // few moderate -> fp32
}
__device__ __forceinline__ float ldv(int f32, const void* p, int i) {
    return f32 ? ((const float*)p)[i] : bf(((const u16*)p)[i]);
}
// fma-chain dot (matches the validated selection math from the passing rounds).
__device__ __forceinline__ float dot3(float x0, float x1, float x2,
                                      float y0, float y1, float y2) {
    return __fmaf_rn(x2, y2, __fmaf_rn(x1, y1, __fmul_rn(x0, y0)));
}
// Monotonic u32 key: ordering on keys == ordering on float distances.
__device__ __forceinline__ u32 mkey32(float d) {
    u32 f = __float_as_uint(d);
    return f ^ (u32)((((int)f) >> 31) | 0x80000000);
}
__device__ __forceinline__ int cellc(float v, float mn, float inv) {
    int c = (int)floorf((v - mn) * inv);
    return min(15, max(0, c));
}

// ---- canon: w2b | w1a | w1b as FP32 table (dtype-normalized, full precision) ----
__global__ __launch_bounds__(256) void k_canon(const void* __restrict__ probe,
                                               const void* __restrict__ w2b,
                                               const void* __restrict__ w1a,
                                               const void* __restrict__ w1b,
                                               float* __restrict__ canon) {
    int f32 = detect_f32(probe);
    int ix = blockIdx.x * 256 + threadIdx.x;       // 0..32767
    const void* src; int j;
    if (ix < 16384)      { src = w2b; j = ix; }          // 64x256
    else if (ix < 28672) { src = w1a; j = ix - 16384; }  // 64x192
    else                 { src = w1b; j = ix - 28672; }  // 64x64
    canon[ix] = ldv(f32, src, j);
}

// ---- prep: pcl -> float4 (x,y,z,sumsq) ----
__global__ __launch_bounds__(256) void k_prep(const void* __restrict__ probe,
                                              const void* __restrict__ pcl,
                                              float4* __restrict__ pcl4) {
    int f32 = detect_f32(probe);
    int i = blockIdx.x * 256 + threadIdx.x;        // 0..8191
    float x = ldv(f32, pcl, i*3+0), y = ldv(f32, pcl, i*3+1), z = ldv(f32, pcl, i*3+2);
    float s = __fadd_rn(__fadd_rn(__fmul_rn(x,x), __fmul_rn(y,y)), __fmul_rn(z,z));
    pcl4[i] = make_float4(x, y, z, s);
}

// ---- grid build: bbox, 16^3 bin counts, prefix, scatter (cell-major). 1 block/batch ----
__global__ __launch_bounds__(512) void k_gbuild(const float4* __restrict__ pcl4,
                                                float* __restrict__ gmeta,
                                                u32* __restrict__ startsG,
                                                float4* __restrict__ psG,
                                                u16* __restrict__ pidxG) {
    __shared__ u32 cnts[4096];                     // 16 KB: counts -> cursors
    __shared__ float rmn[24], rmx[24];             // 8 waves x 3
    __shared__ u32 wsum[8];
    __shared__ float sm[9];                        // mn3, inv3, cw3
    int b = blockIdx.x;
    const float4* src = pcl4 + ((size_t)b << 12);
    int t = threadIdx.x, lane = t & 63, wid = t >> 6;
    // bbox
    float mn0=FLT_MAX, mn1=FLT_MAX, mn2=FLT_MAX, mx0=-FLT_MAX, mx1=-FLT_MAX, mx2=-FLT_MAX;
    for (int i = t; i < 4096; i += 512) {
        float4 p = src[i];
        mn0 = fminf(mn0, p.x); mx0 = fmaxf(mx0, p.x);
        mn1 = fminf(mn1, p.y); mx1 = fmaxf(mx1, p.y);
        mn2 = fminf(mn2, p.z); mx2 = fmaxf(mx2, p.z);
    }
#pragma unroll
    for (int m = 32; m >= 1; m >>= 1) {
        mn0 = fminf(mn0, __shfl_xor(mn0, m)); mx0 = fmaxf(mx0, __shfl_xor(mx0, m));
        mn1 = fminf(mn1, __shfl_xor(mn1, m)); mx1 = fmaxf(mx1, __shfl_xor(mx1, m));
        mn2 = fminf(mn2, __shfl_xor(mn2, m)); mx2 = fmaxf(mx2, __shfl_xor(mx2, m));
    }
    if (lane == 0) {
        rmn[wid*3+0]=mn0; rmn[wid*3+1]=mn1; rmn[wid*3+2]=mn2;
        rmx[wid*3+0]=mx0; rmx[wid*3+1]=mx1; rmx[wid*3+2]=mx2;
    }
    __syncthreads();
    if (t == 0) {
        float gmn[3], gmx[3];
#pragma unroll
        for (int k = 0; k < 3; ++k) { gmn[k] = rmn[k]; gmx[k] = rmx[k]; }
        for (int w = 1; w < 8; ++w)
#pragma unroll
            for (int k = 0; k < 3; ++k) {
                gmn[k] = fminf(gmn[k], rmn[w*3+k]); gmx[k] = fmaxf(gmx[k], rmx[w*3+k]);
            }
#pragma unroll
        for (int k = 0; k < 3; ++k) {
            float ext = fmaxf(gmx[k] - gmn[k], 1e-5f);
            sm[k] = gmn[k]; sm[3+k] = 16.0f / ext; sm[6+k] = ext * 0.0625f;
            gmeta[b*12 + k] = gmn[k]; gmeta[b*12 + 3 + k] = 16.0f / ext;
            gmeta[b*12 + 6 + k] = ext * 0.0625f;
        }
    }
    __syncthreads();
    float m0 = sm[0], m1 = sm[1], m2 = sm[2], i0 = sm[3], i1 = sm[4], i2 = sm[5];
    for (int i = t; i < 4096; i += 512) cnts[i] = 0;
    __syncthreads();
    for (int i = t; i < 4096; i += 512) {
        float4 p = src[i];
        int cell = ((cellc(p.z, m2, i2) << 4) + cellc(p.y, m1, i1)) * 16 + cellc(p.x, m0, i0);
        atomicAdd(&cnts[cell], 1);
    }
    __syncthreads();
    // prefix: 8 bins per thread
    int b0 = t << 3;
    u32 loc[8]; u32 run = 0;
#pragma unroll
    for (int i = 0; i < 8; ++i) { loc[i] = run; run += cnts[b0 + i]; }
    u32 x = run;
#pragma unroll
    for (int off = 1; off < 64; off <<= 1) { u32 v = __shfl_up(x, off); if (lane >= off) x += v; }
    if (lane == 63) wsum[wid] = x;
    __syncthreads();
    if (t == 0) { u32 acc = 0; for (int w = 0; w < 8; ++w) { u32 v = wsum[w]; wsum[w] = acc; acc += v; } }
    __syncthreads();
    u32 texcl = x - run + wsum[wid];
#pragma unroll
    for (int i = 0; i < 8; ++i) startsG[b*4097 + b0 + i] = texcl + loc[i];
    if (t == 0) startsG[b*4097 + 4096] = 4096;
    __syncthreads();
#pragma unroll
    for (int i = 0; i < 8; ++i) cnts[b0 + i] = texcl + loc[i];   // cursors
    __syncthreads();
    for (int i = t; i < 4096; i += 512) {
        float4 p = src[i];
        int cell = ((cellc(p.z, m2, i2) << 4) + cellc(p.y, m1, i1)) * 16 + cellc(p.x, m0, i0);
        u32 pos = atomicAdd(&cnts[cell], 1);
        psG[((size_t)b << 12) + pos] = p;
        pidxG[(b << 12) + pos] = (u16)i;
    }
}

// ---- argmin over M for each noise point; 16 lanes per query; 32 KB chunked tile ----
__global__ __launch_bounds__(256) void k_close(const float4* __restrict__ pcl4,
                                               const void* __restrict__ noise,
                                               u16* __restrict__ cidx) {
    __shared__ __align__(16) float4 tile[2048];
    int f32 = detect_f32(noise);
    int t = threadIdx.x, g = t >> 4, s = t & 15;
    int q = blockIdx.x * 16 + g;                   // global noise-point id
    int b = q >> 13;
    const float4* src = pcl4 + ((size_t)b << 12);
    float x0 = ldv(f32, noise, q*3+0), x1 = ldv(f32, noise, q*3+1), x2 = ldv(f32, noise, q*3+2);
    float sx = __fadd_rn(__fadd_rn(__fmul_rn(x0,x0), __fmul_rn(x1,x1)), __fmul_rn(x2,x2));
    float bd = FLT_MAX; int bi = 0;
    for (int ch = 0; ch < 2; ++ch) {
        __syncthreads();
#pragma unroll
        for (int i = 0; i < 8; ++i) { int ix = t + (i << 8); tile[ix] = src[(ch << 11) + ix]; }
        __syncthreads();
        for (int j = 0; j < 128; ++j) {
            int cl = (j << 4) + s;                 // lane-interleaved: conflict-free LDS
            float4 p = tile[cl];
            float dot = dot3(x0, x1, x2, p.x, p.y, p.z);
            float d = __fadd_rn(__fsub_rn(sx, __fmul_rn(2.0f, dot)), p.w);
            int c = (ch << 11) + cl;               // strictly increasing within thread
            if (d < bd) { bd = d; bi = c; }        // -> first-min on ties
        }
    }
#pragma unroll
    for (int m = 8; m >= 1; m >>= 1) {             // lexicographic (d, idx) merge
        float od = __shfl_xor(bd, m);
        int   oi = __shfl_xor(bi, m);
        if (od < bd || (od == bd && oi < bi)) { bd = od; bi = oi; }
    }
    if (s == 0) cidx[q] = (u16)(bi & 4095);        // masked
}

// ---- k_knng: grid-accelerated exact top-16; one wave (=block) per query ----
#define INS(P) { u32 c_ = (v < k##P); u32 nk = c_ ? v : k##P; u32 nv = c_ ? k##P : v; \
                 u32 ni = c_ ? vi : i##P; u32 nj = c_ ? i##P : vi; \
                 k##P = nk; i##P = ni; v = nv; vi = nj; }
__global__ __launch_bounds__(64) void k_knng(const float4* __restrict__ ps,
                                             const u16* __restrict__ pidx,
                                             const u32* __restrict__ starts,
                                             const float* __restrict__ gmeta,
                                             const float4* __restrict__ pcl4,
                                             u16* __restrict__ knn) {
    __shared__ u32 bkey[2048];                     // 8 KB
    __shared__ u16 bidx[2048];                     // 4 KB
    int lane = threadIdx.x;
    int q = blockIdx.x;                            // 0..8191
    int b = q >> 12;
    const float4* psb = ps + ((size_t)b << 12);
    const u16* pib = pidx + (b << 12);
    const u32* stb = starts + b * 4097;
    const float* gm = gmeta + b * 12;
    float m0 = gm[0], m1 = gm[1], m2 = gm[2];
    float i0v = gm[3], i1v = gm[4], i2v = gm[5];
    float cw0 = gm[6], cw1 = gm[7], cw2 = gm[8];
    float4 Q = pcl4[q];
    float x0 = Q.x, x1 = Q.y, x2 = Q.z, sx = Q.w;
    int cx = cellc(x0, m0, i0v), cy = cellc(x1, m1, i1v), cz = cellc(x2, m2, i2v);
    int cnt = 0, selcnt = -1, overflow = 0, done = 0;
    u32 kth = 0, myres = 0;
    for (int r = 0; r < 16 && !done && !overflow; ++r) {
        int z0 = max(cz - r, 0), z1 = min(cz + r, 15);
        for (int z = z0; z <= z1 && !overflow; ++z) {
            int zb = (z == cz - r) || (z == cz + r);
            int y0 = max(cy - r, 0), y1 = min(cy + r, 15);
            for (int y = y0; y <= y1 && !overflow; ++y) {
                int yb = (y == cy - r) || (y == cy + r);
                int nseg; int sx0[2], sx1[2];
                if (zb || yb) { nseg = 1; sx0[0] = max(cx - r, 0); sx1[0] = min(cx + r, 15); }
                else {                               // interior row: only x = cx±r
                    nseg = 0;
                    if (cx - r >= 0) { sx0[nseg] = cx - r; sx1[nseg] = cx - r; ++nseg; }
                    if (cx + r <= 15) { sx0[nseg] = cx + r; sx1[nseg] = cx + r; ++nseg; }
                }
                for (int sgi = 0; sgi < nseg && !overflow; ++sgi) {
                    u32 c0 = (u32)(((z << 4) + y) * 16 + sx0[sgi]);
                    u32 c1 = (u32)(((z << 4) + y) * 16 + sx1[sgi]);
                    u32 p0 = stb[c0], p1 = stb[c1 + 1];
                    for (u32 bp = p0; bp < p1; bp += 64) {
                        int n = (int)min(64u, p1 - bp);
                        if (cnt + n > 2048) { overflow = 1; break; }
                        if (lane < n) {
                            u32 i = bp + (u32)lane;
                            float4 p = psb[i];
                            float dot = dot3(x0, x1, x2, p.x, p.y, p.z);
                            float d = __fadd_rn(__fsub_rn(sx, __fmul_rn(2.0f, dot)), p.w);
                            bkey[cnt + lane] = mkey32(d);
                            bidx[cnt + lane] = pib[i];
                        }
                        cnt += n;
                    }
                }
            }
        }
        if (overflow) break;
        if (cnt >= 16) {
            // conservative lower bound on any unscanned point's distance^2
            float dmin = 1e30f; int allcover = 1;
            if (cx - r > 0)  { float lo = m0 + (float)(cx - r) * cw0; dmin = fminf(dmin, fmaxf(x0 - lo, 0.f)); allcover = 0; }
            if (cx + r < 15) { float hi = m0 + (float)(cx + r + 1) * cw0; dmin = fminf(dmin, fmaxf(hi - x0, 0.f)); allcover = 0; }
            if (cy - r > 0)  { float lo = m1 + (float)(cy - r) * cw1; dmin = fminf(dmin, fmaxf(x1 - lo, 0.f)); allcover = 0; }
            if (cy + r < 15) { float hi = m1 + (float)(cy + r + 1) * cw1; dmin = fminf(dmin, fmaxf(hi - x1, 0.f)); allcover = 0; }
            if (cz - r > 0)  { float lo = m2 + (float)(cz - r) * cw2; dmin = fminf(dmin, fmaxf(x2 - lo, 0.f)); allcover = 0; }
            if (cz + r < 15) { float hi = m2 + (float)(cz + r + 1) * cw2; dmin = fminf(dmin, fmaxf(hi - x2, 0.f)); allcover = 0; }
            if (selcnt != cnt) {
                __syncthreads();                   // publish appended LDS entries
                // exact tournament: 16 rounds of lex-(key,idx) min, strictly above prev
                u32 pk = 0, pi = 0; int first = 1;
                for (int o = 0; o < 16; ++o) {
                    u32 bk = 0xFFFFFFFFu, bi2 = 0xFFFFu;
                    for (int e = lane; e < cnt; e += 64) {
                        u32 kv = bkey[e]; u32 iv = (u32)bidx[e];
                        bool gt = first || (kv > pk) || (kv == pk && iv > pi);
                        if (gt && ((kv < bk) || (kv == bk && iv < bi2))) { bk = kv; bi2 = iv; }
                    }
#pragma unroll
                    for (int m = 32; m >= 1; m >>= 1) {
                        u32 ok = __shfl_xor(bk, m), oi = __shfl_xor(bi2, m);
                        if (ok < bk || (ok == bk && oi < bi2)) { bk = ok; bi2 = oi; }
                    }
                    if (lane == o) myres = bi2;
                    pk = bk; pi = bi2; first = 0;
                }
                kth = pk; selcnt = cnt;
            }
            float bd2 = dmin * dmin * 0.998f - 1e-4f;
            if (allcover || mkey32(bd2) > kth) done = 1;
        }
    }
    if (overflow) {
        // exact brute-force fallback: per-lane ripple over 64 ascending-idx candidates
        int pbase = b << 12;
        u32 k0=~0u,k1=~0u,k2=~0u,k3=~0u,k4=~0u,k5=~0u,k6=~0u,k7=~0u,
            k8=~0u,k9=~0u,k10=~0u,k11=~0u,k12=~0u,k13=~0u,k14=~0u,k15=~0u;
        u32 i0r=0,i1r=0,i2r=0,i3r=0,i4r=0,i5r=0,i6r=0,i7r=0,
            i8r=0,i9r=0,i10r=0,i11r=0,i12r=0,i13r=0,i14r=0,i15r=0;
        for (int j = 0; j < 64; ++j) {
            int cin = (j << 6) + lane;             // ascending per lane -> ties keep low idx
            float4 p = pcl4[pbase + cin];
            float dot = dot3(x0, x1, x2, p.x, p.y, p.z);
            float d = __fadd_rn(__fsub_rn(sx, __fmul_rn(2.0f, dot)), p.w);
            u32 v = mkey32(d); u32 vi = (u32)cin;
            if (v < k15) {
                { u32 c_=(v<k0); u32 nk=c_?v:k0; u32 nv=c_?k0:v; u32 ni=c_?vi:i0r; u32 nj=c_?i0r:vi; k0=nk;i0r=ni;v=nv;vi=nj; }
                { u32 c_=(v<k1); u32 nk=c_?v:k1; u32 nv=c_?k1:v; u32 ni=c_?vi:i1r; u32 nj=c_?i1r:vi; k1=nk;i1r=ni;v=nv;vi=nj; }
                { u32 c_=(v<k2); u32 nk=c_?v:k2; u32 nv=c_?k2:v; u32 ni=c_?vi:i2r; u32 nj=c_?i2r:vi; k2=nk;i2r=ni;v=nv;vi=nj; }
                { u32 c_=(v<k3); u32 nk=c_?v:k3; u32 nv=c_?k3:v; u32 ni=c_?vi:i3r; u32 nj=c_?i3r:vi; k3=nk;i3r=ni;v=nv;vi=nj; }
                { u32 c_=(v<k4); u32 nk=c_?v:k4; u32 nv=c_?k4:v; u32 ni=c_?vi:i4r; u32 nj=c_?i4r:vi; k4=nk;i4r=ni;v=nv;vi=nj; }
                { u32 c_=(v<k5); u32 nk=c_?v:k5; u32 nv=c_?k5:v; u32 ni=c_?vi:i5r; u32 nj=c_?i5r:vi; k5=nk;i5r=ni;v=nv;vi=nj; }
                { u32 c_=(v<k6); u32 nk=c_?v:k6; u32 nv=c_?k6:v; u32 ni=c_?vi:i6r; u32 nj=c_?i6r:vi; k6=nk;i6r=ni;v=nv;vi=nj; }
                { u32 c_=(v<k7); u32 nk=c_?v:k7; u32 nv=c_?k7:v; u32 ni=c_?vi:i7r; u32 nj=c_?i7r:vi; k7=nk;i7r=ni;v=nv;vi=nj; }
                { u32 c_=(v<k8); u32 nk=c_?v:k8; u32 nv=c_?k8:v; u32 ni=c_?vi:i8r; u32 nj=c_?i8r:vi; k8=nk;i8r=ni;v=nv;vi=nj; }
                { u32 c_=(v<k9); u32 nk=c_?v:k9; u32 nv=c_?k9:v; u32 ni=c_?vi:i9r; u32 nj=c_?i9r:vi; k9=nk;i9r=ni;v=nv;vi=nj; }
                { u32 c_=(v<k10); u32 nk=c_?v:k10; u32 nv=c_?k10:v; u32 ni=c_?vi:i10r; u32 nj=c_?i10r:vi; k10=nk;i10r=ni;v=nv;vi=nj; }
                { u32 c_=(v<k11); u32 nk=c_?v:k11; u32 nv=c_?k11:v; u32 ni=c_?vi:i11r; u32 nj=c_?i11r:vi; k11=nk;i11r=ni;v=nv;vi=nj; }
                { u32 c_=(v<k12); u32 nk=c_?v:k12; u32 nv=c_?k12:v; u32 ni=c_?vi:i12r; u32 nj=c_?i12r:vi; k12=nk;i12r=ni;v=nv;vi=nj; }
                { u32 c_=(v<k13); u32 nk=c_?v:k13; u32 nv=c_?k13:v; u32 ni=c_?vi:i13r; u32 nj=c_?i13r:vi; k13=nk;i13r=ni;v=nv;vi=nj; }
                { u32 c_=(v<k14); u32 nk=c_?v:k14; u32 nv=c_?k14:v; u32 ni=c_?vi:i14r; u32 nj=c_?i14r:vi; k14=nk;i14r=ni;v=nv;vi=nj; }
                { u32 c_=(v<k15); u32 nk=c_?v:k15; u32 nv=c_?k15:v; u32 ni=c_?vi:i15r; u32 nj=c_?i15r:vi; k15=nk;i15r=ni;v=nv;vi=nj; }
            }
        }
        // shift-register tournament across 64 lanes, lex (key, idx)
        for (int o = 0; o < 16; ++o) {
            u32 bk = k0, bi2 = i0r;
#pragma unroll
            for (int m = 32; m >= 1; m >>= 1) {
                u32 ok = __shfl_xor(bk, m), oi = __shfl_xor(bi2, m);
                if (ok < bk || (ok == bk && oi < bi2)) { bk = ok; bi2 = oi; }
            }
            if (lane == o) myres = bi2;
            if (k0 == bk && i0r == bi2) {          // winner lane pops its head
                k0=k1; i0r=i1r; k1=k2; i1r=i2r; k2=k3; i2r=i3r; k3=k4; i3r=i4r;
                k4=k5; i4r=i5r; k5=k6; i5r=i6r; k6=k7; i6r=i7r; k7=k8; i7r=i8r;
                k8=k9; i8r=i9r; k9=k10; i9r=i10r; k10=k11; i10r=i11r; k11=k12; i11r=i12r;
                k12=k13; i12r=i13r; k13=k14; i13r=i14r; k14=k15; i14r=i15r;
                k15=~0u; i15r=0xFFFFu;
            }
        }
    }
    if (lane < 16) knn[((size_t)q << 4) + lane] = (u16)myres;
}

// ---- fused tail: 4 queries per wave (weight-load amortization), 16 per block ----
__global__ __launch_bounds__(256) void k_tail(const float4* __restrict__ pcl4,
                                              const void* __restrict__ noise,
                                              const void* __restrict__ feat,
                                              const u16* __restrict__ cidx,
                                              const u16* __restrict__ knn,
                                              const void* __restrict__ w2a,
                                              const void* __restrict__ b2a,
                                              const void* __restrict__ g2a,
                                              const void* __restrict__ bt2a,
                                              const float* __restrict__ canon,
                                              const void* __restrict__ b2b,
                                              const void* __restrict__ b1a,
                                              const void* __restrict__ g1a,
                                              const void* __restrict__ bt1a,
                                              const void* __restrict__ b1b,
                                              void* __restrict__ outp) {
    __shared__ float w2at[6][256];
    __shared__ float sc2[256], of2[256];
    __shared__ float b2bf[64], s1[64], o1[64], b1f[64];
    __shared__ __align__(16) float hb[4][4][256];
    __shared__ __align__(16) float dfs[4][4][192];
    __shared__ __align__(16) float h1s[4][4][64];
    __shared__ float dpb[4][4][16][6];
    __shared__ float wbuf[4][4][16];
    __shared__ int   jbuf[4][4][16];
    __shared__ float wsb[4][4];

    int f32 = detect_f32(noise);
    int t = threadIdx.x;
    {
        float s2 = ldv(f32, g2a, t) / sqrtf(1.0f + 1e-5f);
        sc2[t] = s2;
        of2[t] = ldv(f32, b2a, t) * s2 + ldv(f32, bt2a, t);
#pragma unroll
        for (int c = 0; c < 6; ++c) w2at[c][t] = ldv(f32, w2a, t*6+c);
        if (t < 64) {
            b2bf[t] = ldv(f32, b2b, t);
            float s = ldv(f32, g1a, t) / sqrtf(1.0f + 1e-5f);
            s1[t] = s; o1[t] = ldv(f32, b1a, t) * s + ldv(f32, bt1a, t); b1f[t] = ldv(f32, b1b, t);
        }
    }
    int lane = t & 63, wv = t >> 6;
    int qbase = blockIdx.x * 16 + wv * 4;
    {
        int ql = lane >> 4, s = lane & 15;
        int q = qbase + ql;
        int b = q >> 13;
        int pbase = (b << 12);
        int ci = ((int)cidx[q]) & 4095;
        float4 cp = pcl4[pbase + ci];
        float x0 = ldv(f32, noise, q*3+0), x1 = ldv(f32, noise, q*3+1), x2 = ldv(f32, noise, q*3+2);
        float e = 0.0f;
        if (s >= 1) {
            int jk = ((int)knn[(size_t)(pbase + ci) * 16 + s]) & 4095;
            float4 p = pcl4[pbase + jk];
            float d0 = p.x - x0, d1 = p.y - x1, d2 = p.z - x2;
            float dst = sqrtf(__fadd_rn(__fadd_rn(__fmul_rn(d0,d0), __fmul_rn(d1,d1)), __fmul_rn(d2,d2)));
            e = expf(-10.0f * dst);
            dpb[wv][ql][s][0] = d0; dpb[wv][ql][s][1] = d1; dpb[wv][ql][s][2] = d2;
            dpb[wv][ql][s][3] = cp.x; dpb[wv][ql][s][4] = cp.y; dpb[wv][ql][s][5] = cp.z;
            jbuf[wv][ql][s] = jk;
        }
        float es = e;
#pragma unroll
        for (int m = 8; m >= 1; m >>= 1) es += __shfl_xor(es, m, 16);
        float den = es + 1e-7f;
        if (s >= 1) wbuf[wv][ql][s] = e / den;
        if (s == 0) wsb[wv][ql] = es / den;
    }
    __syncthreads();

    float cf[4], co[4];
#pragma unroll
    for (int ql = 0; ql < 4; ++ql) {
        int q = qbase + ql;
        int b = q >> 13;
        int pbase = (b << 12);
        int ci = ((int)cidx[q]) & 4095;
        size_t fcb = ((size_t)(pbase + ci)) << 6;
        float c0, c1 = 0.0f;
        if (f32) {
            const float* ff = (const float*)feat;
            c0 = ff[fcb + lane];
#pragma unroll
            for (int k = 1; k < 16; ++k)
                c1 += wbuf[wv][ql][k] * ff[(((size_t)(pbase + jbuf[wv][ql][k])) << 6) + lane];
        } else {
            const u16* fb = (const u16*)feat;
            c0 = bf(fb[fcb + lane]);
#pragma unroll
            for (int k = 1; k < 16; ++k)
                c1 += wbuf[wv][ql][k] * bf(fb[(((size_t)(pbase + jbuf[wv][ql][k])) << 6) + lane]);
        }
        cf[ql] = c0; co[ql] = c1;
    }

    float wa[4][6], scr[4], ofr[4];
#pragma unroll
    for (int r = 0; r < 4; ++r) {
        int ch = lane + (r << 6);
#pragma unroll
        for (int c = 0; c < 6; ++c) wa[r][c] = w2at[c][ch];
        scr[r] = sc2[ch]; ofr[r] = of2[ch];
    }
    float hv[4][4];
#pragma unroll
    for (int ql = 0; ql < 4; ++ql)
#pragma unroll
        for (int r = 0; r < 4; ++r) hv[ql][r] = 0.0f;
#pragma unroll
    for (int k = 1; k < 16; ++k) {
#pragma unroll
        for (int ql = 0; ql < 4; ++ql) {
            float p0 = dpb[wv][ql][k][0], p1 = dpb[wv][ql][k][1], p2 = dpb[wv][ql][k][2];
            float p3 = dpb[wv][ql][k][3], p4 = dpb[wv][ql][k][4], p5 = dpb[wv][ql][k][5];
            float wk = wbuf[wv][ql][k];
#pragma unroll
            for (int r = 0; r < 4; ++r) {
                float z = p0*wa[r][0] + p1*wa[r][1] + p2*wa[r][2]
                        + p3*wa[r][3] + p4*wa[r][4] + p5*wa[r][5];
                z = z * scr[r] + ofr[r];
                z = fmaxf(z, 0.0f);
                hv[ql][r] += wk * z;
            }
        }
    }
#pragma unroll
    for (int ql = 0; ql < 4; ++ql)
#pragma unroll
        for (int r = 0; r < 4; ++r) hb[wv][ql][lane + (r << 6)] = hv[ql][r];
    __syncthreads();

    float acc[4];
#pragma unroll
    for (int ql = 0; ql < 4; ++ql) acc[ql] = b2bf[lane] * wsb[wv][ql];
    {
        const float4* wrow = reinterpret_cast<const float4*>(canon + (lane << 8));
#pragma unroll 4
        for (int i = 0; i < 64; ++i) {
            float4 w = wrow[i];
#pragma unroll
            for (int ql = 0; ql < 4; ++ql) {
                const float4* hrow = reinterpret_cast<const float4*>(&hb[wv][ql][0]);
                float4 h = hrow[i];
                acc[ql] += w.x*h.x + w.y*h.y + w.z*h.z + w.w*h.w;
            }
        }
    }
#pragma unroll
    for (int ql = 0; ql < 4; ++ql) {
        dfs[wv][ql][lane]       = cf[ql];
        dfs[wv][ql][64 + lane]  = co[ql];
        dfs[wv][ql][128 + lane] = acc[ql];
    }
    __syncthreads();

    float acc1[4] = {0.0f, 0.0f, 0.0f, 0.0f};
    {
        const float4* wr = reinterpret_cast<const float4*>(canon + 16384 + lane * 192);
#pragma unroll 4
        for (int i = 0; i < 48; ++i) {
            float4 w = wr[i];
#pragma unroll
            for (int ql = 0; ql < 4; ++ql) {
                const float4* dv = reinterpret_cast<const float4*>(&dfs[wv][ql][0]);
                float4 a = dv[i];
                acc1[ql] += w.x*a.x + w.y*a.y + w.z*a.z + w.w*a.w;
            }
        }
    }
#pragma unroll
    for (int ql = 0; ql < 4; ++ql) {
        float z1 = acc1[ql] * s1[lane] + o1[lane];
        z1 = fmaxf(z1, 0.0f);
        h1s[wv][ql][lane] = z1;
    }
    __syncthreads();

    float a2[4];
#pragma unroll
    for (int ql = 0; ql < 4; ++ql) a2[ql] = b1f[lane];
    {
        const float4* wr2 = reinterpret_cast<const float4*>(canon + 28672 + (lane << 6));
#pragma unroll
        for (int i = 0; i < 16; ++i) {
            float4 w = wr2[i];
#pragma unroll
            for (int ql = 0; ql < 4; ++ql) {
                const float4* hv2 = reinterpret_cast<const float4*>(&h1s[wv][ql][0]);
                float4 a = hv2[i];
                a2[ql] += w.x*a.x + w.y*a.y + w.z*a.z + w.w*a.w;
            }
        }
    }
#pragma unroll
    for (int ql = 0; ql < 4; ++ql) {
        size_t ob = ((size_t)(qbase + ql) << 6) + lane;
        if (f32) ((float*)outp)[ob] = a2[ql];
        else     ((u16*)outp)[ob]   = f2bf(a2[ql]);
    }
}

extern "C" void kernel_launch(void* const* d_in, const int* in_sizes, int n_in,
                              void* d_out, int out_size, void* d_ws, size_t ws_size,
                              hipStream_t stream) {
    const void* pcl   = d_in[0];
    const void* noise = d_in[1];
    const void* feat  = d_in[2];
    const void* w2a   = d_in[3];
    const void* b2a   = d_in[4];
    const void* g2a   = d_in[5];
    const void* bt2a  = d_in[6];
    const void* w2b   = d_in[7];
    const void* b2b   = d_in[8];
    const void* w1a   = d_in[9];
    const void* b1a   = d_in[10];
    const void* g1a   = d_in[11];
    const void* bt1a  = d_in[12];
    const void* w1b   = d_in[13];
    const void* b1b   = d_in[14];

    char* ws = (char*)d_ws;
    float4* pcl4 = (float4*)ws;                    // 128 KB
    u16* cidx = (u16*)(ws + 131072);               // 32 KB
    u16* knn  = (u16*)(ws + 163840);               // 256 KB
    float* canon = (float*)(ws + 425984);          // 128 KB
    float4* psG = (float4*)(ws + 557056);          // 128 KB: cell-major points
    u16* pidxG = (u16*)(ws + 688128);              // 16 KB
    u32* startsG = (u32*)(ws + 704512);            // 32.8 KB: 2 x 4097
    float* gmeta = (float*)(ws + 737792);          // 96 B
    // total workspace: ~738 KB

    k_canon <<<128,  256, 0, stream>>>(noise, w2b, w1a, w1b, canon);
    k_prep  <<<32,   256, 0, stream>>>(noise, pcl, pcl4);
    k_gbuild<<<2,    512, 0, stream>>>(pcl4, gmeta, startsG, psG, pidxG);
    k_close <<<1024, 256, 0, stream>>>(pcl4, noise, cidx);
    k_knng  <<<8192, 64,  0, stream>>>(psG, pidxG, startsG, gmeta, pcl4, knn);
    k_tail  <<<1024, 256, 0, stream>>>(pcl4, noise, feat, cidx, knn,
                                       w2a, b2a, g2a, bt2a, canon, b2b,
                                       b1a, g1a, bt1a, b1b, d_out);
}

// Round 12
// 381.094 us; speedup vs baseline: 1.0624x; 1.0624x over previous
//
#include <hip/hip_runtime.h>
#include <float.h>

typedef unsigned short u16;
typedef unsigned int u32;

// B=2, N=8192, M=4096, C=64, K=16, HID=256
__device__ __forceinline__ float bf(u16 u) { return __uint_as_float(((u32)u) << 16); }
__device__ __forceinline__ u16 f2bf(float v) {
    u32 x = __float_as_uint(v);
    u32 r = x + 0x7fffu + ((x >> 16) & 1u);
    return (u16)(r >> 16);
}
// Dtype probe on EVEN u16 positions of a large ~N(0,1) buffer (pcl_noise).
__device__ __forceinline__ int detect_f32(const void* probe) {
    const u16* u = (const u16*)probe;
    u16 v = u[(threadIdx.x & 63) * 2];
    int e = (int)((v >> 7) & 0xFF);
    int moderate = (e >= 100) && (e <= 140);
    return __popcll(__ballot(moderate)) < 48;   // few moderate -> fp32
}
__device__ __forceinline__ float ldv(int f32, const void* p, int i) {
    return f32 ? ((const float*)p)[i] : bf(((const u16*)p)[i]);
}
// fma-chain dot (matches the validated selection math from the passing rounds).
__device__ __forceinline__ float dot3(float x0, float x1, float x2,
                                      float y0, float y1, float y2) {
    return __fmaf_rn(x2, y2, __fmaf_rn(x1, y1, __fmul_rn(x0, y0)));
}
// Monotonic u32 key: ordering on keys == ordering on float distances.
__device__ __forceinline__ u32 mkey32(float d) {
    u32 f = __float_as_uint(d);
    return f ^ (u32)((((int)f) >> 31) | 0x80000000);
}

// ---- canon: w2b | w1a | w1b as FP32 table (dtype-normalized, full precision) ----
__global__ __launch_bounds__(256) void k_canon(const void* __restrict__ probe,
                                               const void* __restrict__ w2b,
                                               const void* __restrict__ w1a,
                                               const void* __restrict__ w1b,
                                               float* __restrict__ canon) {
    int f32 = detect_f32(probe);
    int ix = blockIdx.x * 256 + threadIdx.x;       // 0..32767
    const void* src; int j;
    if (ix < 16384)      { src = w2b; j = ix; }          // 64x256
    else if (ix < 28672) { src = w1a; j = ix - 16384; }  // 64x192
    else                 { src = w1b; j = ix - 28672; }  // 64x64
    canon[ix] = ldv(f32, src, j);
}

// ---- prep: pcl -> float4 (x,y,z,sumsq) ----
__global__ __launch_bounds__(256) void k_prep(const void* __restrict__ probe,
                                              const void* __restrict__ pcl,
                                              float4* __restrict__ pcl4) {
    int f32 = detect_f32(probe);
    int i = blockIdx.x * 256 + threadIdx.x;        // 0..8191
    float x = ldv(f32, pcl, i*3+0), y = ldv(f32, pcl, i*3+1), z = ldv(f32, pcl, i*3+2);
    float s = __fadd_rn(__fadd_rn(__fmul_rn(x,x), __fmul_rn(y,y)), __fmul_rn(z,z));
    pcl4[i] = make_float4(x, y, z, s);
}

// ---- argmin over M for each noise point; 16 lanes per query; 32 KB chunked tile ----
__global__ __launch_bounds__(256) void k_close(const float4* __restrict__ pcl4,
                                               const void* __restrict__ noise,
                                               u16* __restrict__ cidx) {
    __shared__ __align__(16) float4 tile[2048];
    int f32 = detect_f32(noise);
    int t = threadIdx.x, g = t >> 4, s = t & 15;
    int q = blockIdx.x * 16 + g;                   // global noise-point id
    int b = q >> 13;
    const float4* src = pcl4 + ((size_t)b << 12);
    float x0 = ldv(f32, noise, q*3+0), x1 = ldv(f32, noise, q*3+1), x2 = ldv(f32, noise, q*3+2);
    float sx = __fadd_rn(__fadd_rn(__fmul_rn(x0,x0), __fmul_rn(x1,x1)), __fmul_rn(x2,x2));
    float bd = FLT_MAX; int bi = 0;
    for (int ch = 0; ch < 2; ++ch) {
        __syncthreads();
#pragma unroll
        for (int i = 0; i < 8; ++i) { int ix = t + (i << 8); tile[ix] = src[(ch << 11) + ix]; }
        __syncthreads();
        for (int j = 0; j < 128; ++j) {
            int cl = (j << 4) + s;                 // lane-interleaved: conflict-free LDS
            float4 p = tile[cl];
            float dot = dot3(x0, x1, x2, p.x, p.y, p.z);
            float d = __fadd_rn(__fsub_rn(sx, __fmul_rn(2.0f, dot)), p.w);
            int c = (ch << 11) + cl;               // strictly increasing within thread
            if (d < bd) { bd = d; bi = c; }        // -> first-min on ties
        }
    }
#pragma unroll
    for (int m = 8; m >= 1; m >>= 1) {             // lexicographic (d, idx) merge
        float od = __shfl_xor(bd, m);
        int   oi = __shfl_xor(bi, m);
        if (od < bd || (od == bd && oi < bi)) { bd = od; bi = oi; }
    }
    if (s == 0) cidx[q] = (u16)(bi & 4095);        // masked
}

// ---- k_knnh: exact top-16 via monotone histogram radix-select; 1 wave/query ----
// 256 thr = 4 waves = 4 queries; sample->scale, hist pass, prefix->b*, gather,
// rank-select. Binning is a monotone function of d, so {bin<=b*} provably
// contains the true top-16; survivors get exact lex-(key,idx) rank selection.
__global__ __launch_bounds__(256) void k_knnh(const float4* __restrict__ pcl4,
                                              u16* __restrict__ knn) {
    __shared__ u32 hist[4][256];                   // 4 KB
    __shared__ u32 skey[4][256];                   // 4 KB survivors
    __shared__ u16 sidx[4][256];                   // 2 KB
    __shared__ u32 scnt[4];
    int t = threadIdx.x, lane = t & 63, wv = t >> 6;
    int q = blockIdx.x * 4 + wv;                   // 0..8191
    int b = q >> 12;
    const float4* src = pcl4 + ((size_t)b << 12);
    float4 Q = src[q & 4095];
    float x0 = Q.x, x1 = Q.y, x2 = Q.z, sx = Q.w;
    // zero hist (per wave), cursor
    for (int i = lane; i < 256; i += 64) hist[wv][i] = 0;
    if (lane == 0) scnt[wv] = 0;
    // sample pass: 64 candidates -> scale estimate (any scale is exact; only balance varies)
    float dmn, dmx;
    {
        float4 p = src[lane];
        float dot = dot3(x0, x1, x2, p.x, p.y, p.z);
        float d = __fadd_rn(__fsub_rn(sx, __fmul_rn(2.0f, dot)), p.w);
        dmn = d; dmx = d;
#pragma unroll
        for (int m = 32; m >= 1; m >>= 1) {
            dmn = fminf(dmn, __shfl_xor(dmn, m));
            dmx = fmaxf(dmx, __shfl_xor(dmx, m));
        }
    }
    float sc = 1024.0f / fmaxf(dmx - dmn, 1e-20f); // fine bins over lowest quarter
    __syncthreads();
    // hist pass
    for (int j = 0; j < 64; ++j) {
        float4 p = src[(j << 6) + lane];
        float dot = dot3(x0, x1, x2, p.x, p.y, p.z);
        float d = __fadd_rn(__fsub_rn(sx, __fmul_rn(2.0f, dot)), p.w);
        float fb = fminf(fmaxf((d - dmn) * sc, 0.0f), 255.0f);
        atomicAdd(&hist[wv][(int)fb], 1u);
    }
    __syncthreads();
    // prefix over 256 bins (4/lane) -> first bin with cum >= 16
    int bstar;
    {
        u32 c0 = hist[wv][4*lane], c1 = hist[wv][4*lane+1];
        u32 c2 = hist[wv][4*lane+2], c3 = hist[wv][4*lane+3];
        u32 loc = c0 + c1 + c2 + c3;
        u32 x = loc;
#pragma unroll
        for (int off = 1; off < 64; off <<= 1) { u32 v = __shfl_up(x, off); if (lane >= off) x += v; }
        u32 excl = x - loc;
        int cand = 999;
        if (excl + c0 >= 16u) cand = 4*lane;
        else if (excl + c0 + c1 >= 16u) cand = 4*lane + 1;
        else if (excl + c0 + c1 + c2 >= 16u) cand = 4*lane + 2;
        else if (excl + loc >= 16u) cand = 4*lane + 3;
#pragma unroll
        for (int m = 32; m >= 1; m >>= 1) cand = min(cand, __shfl_xor(cand, m));
        bstar = cand;                              // always <= 255 (4096 >= 16)
    }
    // gather pass: survivors = all candidates with bin <= b*
    for (int j = 0; j < 64; ++j) {
        int cin = (j << 6) + lane;
        float4 p = src[cin];
        float dot = dot3(x0, x1, x2, p.x, p.y, p.z);
        float d = __fadd_rn(__fsub_rn(sx, __fmul_rn(2.0f, dot)), p.w);
        float fb = fminf(fmaxf((d - dmn) * sc, 0.0f), 255.0f);
        if ((int)fb <= bstar) {
            u32 pos = atomicAdd(&scnt[wv], 1u);
            if (pos < 256u) { skey[wv][pos] = mkey32(d); sidx[wv][pos] = (u16)cin; }
        }
    }
    __syncthreads();
    u32 n = scnt[wv];
    if (n <= 256u) {
        // rank-select: rank = #survivors lex-(key,idx)-smaller; rank<16 -> output
        for (u32 e = (u32)lane; e < n; e += 64u) {
            u32 k = skey[wv][e]; u32 i = (u32)sidx[wv][e];
            int rank = 0;
            for (u32 j = 0; j < n; ++j) {
                u32 kj = skey[wv][j]; u32 ij = (u32)sidx[wv][j];
                rank += (kj < k) || (kj == k && ij < i);
            }
            if (rank < 16) knn[((size_t)q << 4) + rank] = (u16)i;
        }
    } else {
        // exact brute-force fallback (validated ripple + shift-register tournament)
        u32 k0=~0u,k1=~0u,k2=~0u,k3=~0u,k4=~0u,k5=~0u,k6=~0u,k7=~0u,
            k8=~0u,k9=~0u,k10=~0u,k11=~0u,k12=~0u,k13=~0u,k14=~0u,k15=~0u;
        u32 i0r=0,i1r=0,i2r=0,i3r=0,i4r=0,i5r=0,i6r=0,i7r=0,
            i8r=0,i9r=0,i10r=0,i11r=0,i12r=0,i13r=0,i14r=0,i15r=0;
        for (int j = 0; j < 64; ++j) {
            int cin = (j << 6) + lane;             // ascending per lane -> stable ties
            float4 p = src[cin];
            float dot = dot3(x0, x1, x2, p.x, p.y, p.z);
            float d = __fadd_rn(__fsub_rn(sx, __fmul_rn(2.0f, dot)), p.w);
            u32 v = mkey32(d); u32 vi = (u32)cin;
            if (v < k15) {
                { u32 c_=(v<k0); u32 nk=c_?v:k0; u32 nv=c_?k0:v; u32 ni=c_?vi:i0r; u32 nj=c_?i0r:vi; k0=nk;i0r=ni;v=nv;vi=nj; }
                { u32 c_=(v<k1); u32 nk=c_?v:k1; u32 nv=c_?k1:v; u32 ni=c_?vi:i1r; u32 nj=c_?i1r:vi; k1=nk;i1r=ni;v=nv;vi=nj; }
                { u32 c_=(v<k2); u32 nk=c_?v:k2; u32 nv=c_?k2:v; u32 ni=c_?vi:i2r; u32 nj=c_?i2r:vi; k2=nk;i2r=ni;v=nv;vi=nj; }
                { u32 c_=(v<k3); u32 nk=c_?v:k3; u32 nv=c_?k3:v; u32 ni=c_?vi:i3r; u32 nj=c_?i3r:vi; k3=nk;i3r=ni;v=nv;vi=nj; }
                { u32 c_=(v<k4); u32 nk=c_?v:k4; u32 nv=c_?k4:v; u32 ni=c_?vi:i4r; u32 nj=c_?i4r:vi; k4=nk;i4r=ni;v=nv;vi=nj; }
                { u32 c_=(v<k5); u32 nk=c_?v:k5; u32 nv=c_?k5:v; u32 ni=c_?vi:i5r; u32 nj=c_?i5r:vi; k5=nk;i5r=ni;v=nv;vi=nj; }
                { u32 c_=(v<k6); u32 nk=c_?v:k6; u32 nv=c_?k6:v; u32 ni=c_?vi:i6r; u32 nj=c_?i6r:vi; k6=nk;i6r=ni;v=nv;vi=nj; }
                { u32 c_=(v<k7); u32 nk=c_?v:k7; u32 nv=c_?k7:v; u32 ni=c_?vi:i7r; u32 nj=c_?i7r:vi; k7=nk;i7r=ni;v=nv;vi=nj; }
                { u32 c_=(v<k8); u32 nk=c_?v:k8; u32 nv=c_?k8:v; u32 ni=c_?vi:i8r; u32 nj=c_?i8r:vi; k8=nk;i8r=ni;v=nv;vi=nj; }
                { u32 c_=(v<k9); u32 nk=c_?v:k9; u32 nv=c_?k9:v; u32 ni=c_?vi:i9r; u32 nj=c_?i9r:vi; k9=nk;i9r=ni;v=nv;vi=nj; }
                { u32 c_=(v<k10); u32 nk=c_?v:k10; u32 nv=c_?k10:v; u32 ni=c_?vi:i10r; u32 nj=c_?i10r:vi; k10=nk;i10r=ni;v=nv;vi=nj; }
                { u32 c_=(v<k11); u32 nk=c_?v:k11; u32 nv=c_?k11:v; u32 ni=c_?vi:i11r; u32 nj=c_?i11r:vi; k11=nk;i11r=ni;v=nv;vi=nj; }
                { u32 c_=(v<k12); u32 nk=c_?v:k12; u32 nv=c_?k12:v; u32 ni=c_?vi:i12r; u32 nj=c_?i12r:vi; k12=nk;i12r=ni;v=nv;vi=nj; }
                { u32 c_=(v<k13); u32 nk=c_?v:k13; u32 nv=c_?k13:v; u32 ni=c_?vi:i13r; u32 nj=c_?i13r:vi; k13=nk;i13r=ni;v=nv;vi=nj; }
                { u32 c_=(v<k14); u32 nk=c_?v:k14; u32 nv=c_?k14:v; u32 ni=c_?vi:i14r; u32 nj=c_?i14r:vi; k14=nk;i14r=ni;v=nv;vi=nj; }
                { u32 c_=(v<k15); u32 nk=c_?v:k15; u32 nv=c_?k15:v; u32 ni=c_?vi:i15r; u32 nj=c_?i15r:vi; k15=nk;i15r=ni;v=nv;vi=nj; }
            }
        }
        u32 myres = 0;
        for (int o = 0; o < 16; ++o) {
            u32 bk = k0, bi2 = i0r;
#pragma unroll
            for (int m = 32; m >= 1; m >>= 1) {
                u32 ok = __shfl_xor(bk, m), oi = __shfl_xor(bi2, m);
                if (ok < bk || (ok == bk && oi < bi2)) { bk = ok; bi2 = oi; }
            }
            if (lane == o) myres = bi2;
            if (k0 == bk && i0r == bi2) {          // winner lane pops its head
                k0=k1; i0r=i1r; k1=k2; i1r=i2r; k2=k3; i2r=i3r; k3=k4; i3r=i4r;
                k4=k5; i4r=i5r; k5=k6; i5r=i6r; k6=k7; i6r=i7r; k7=k8; i7r=i8r;
                k8=k9; i8r=i9r; k9=k10; i9r=i10r; k10=k11; i10r=i11r; k11=k12; i11r=i12r;
                k12=k13; i12r=i13r; k13=k14; i13r=i14r; k14=k15; i14r=i15r;
                k15=~0u; i15r=0xFFFFu;
            }
        }
        if (lane < 16) knn[((size_t)q << 4) + lane] = (u16)myres;
    }
}

// ---- fused tail: 4 queries per wave (weight-load amortization), 16 per block ----
__global__ __launch_bounds__(256) void k_tail(const float4* __restrict__ pcl4,
                                              const void* __restrict__ noise,
                                              const void* __restrict__ feat,
                                              const u16* __restrict__ cidx,
                                              const u16* __restrict__ knn,
                                              const void* __restrict__ w2a,
                                              const void* __restrict__ b2a,
                                              const void* __restrict__ g2a,
                                              const void* __restrict__ bt2a,
                                              const float* __restrict__ canon,
                                              const void* __restrict__ b2b,
                                              const void* __restrict__ b1a,
                                              const void* __restrict__ g1a,
                                              const void* __restrict__ bt1a,
                                              const void* __restrict__ b1b,
                                              void* __restrict__ outp) {
    __shared__ float w2at[6][256];
    __shared__ float sc2[256], of2[256];
    __shared__ float b2bf[64], s1[64], o1[64], b1f[64];
    __shared__ __align__(16) float hb[4][4][256];
    __shared__ __align__(16) float dfs[4][4][192];
    __shared__ __align__(16) float h1s[4][4][64];
    __shared__ float dpb[4][4][16][6];
    __shared__ float wbuf[4][4][16];
    __shared__ int   jbuf[4][4][16];
    __shared__ float wsb[4][4];

    int f32 = detect_f32(noise);
    int t = threadIdx.x;
    {
        float s2 = ldv(f32, g2a, t) / sqrtf(1.0f + 1e-5f);
        sc2[t] = s2;
        of2[t] = ldv(f32, b2a, t) * s2 + ldv(f32, bt2a, t);
#pragma unroll
        for (int c = 0; c < 6; ++c) w2at[c][t] = ldv(f32, w2a, t*6+c);
        if (t < 64) {
            b2bf[t] = ldv(f32, b2b, t);
            float s = ldv(f32, g1a, t) / sqrtf(1.0f + 1e-5f);
            s1[t] = s; o1[t] = ldv(f32, b1a, t) * s + ldv(f32, bt1a, t); b1f[t] = ldv(f32, b1b, t);
        }
    }
    int lane = t & 63, wv = t >> 6;
    int qbase = blockIdx.x * 16 + wv * 4;
    {
        int ql = lane >> 4, s = lane & 15;
        int q = qbase + ql;
        int b = q >> 13;
        int pbase = (b << 12);
        int ci = ((int)cidx[q]) & 4095;
        float4 cp = pcl4[pbase + ci];
        float x0 = ldv(f32, noise, q*3+0), x1 = ldv(f32, noise, q*3+1), x2 = ldv(f32, noise, q*3+2);
        float e = 0.0f;
        if (s >= 1) {
            int jk = ((int)knn[(size_t)(pbase + ci) * 16 + s]) & 4095;
            float4 p = pcl4[pbase + jk];
            float d0 = p.x - x0, d1 = p.y - x1, d2 = p.z - x2;
            float dst = sqrtf(__fadd_rn(__fadd_rn(__fmul_rn(d0,d0), __fmul_rn(d1,d1)), __fmul_rn(d2,d2)));
            e = expf(-10.0f * dst);
            dpb[wv][ql][s][0] = d0; dpb[wv][ql][s][1] = d1; dpb[wv][ql][s][2] = d2;
            dpb[wv][ql][s][3] = cp.x; dpb[wv][ql][s][4] = cp.y; dpb[wv][ql][s][5] = cp.z;
            jbuf[wv][ql][s] = jk;
        }
        float es = e;
#pragma unroll
        for (int m = 8; m >= 1; m >>= 1) es += __shfl_xor(es, m, 16);
        float den = es + 1e-7f;
        if (s >= 1) wbuf[wv][ql][s] = e / den;
        if (s == 0) wsb[wv][ql] = es / den;
    }
    __syncthreads();

    float cf[4], co[4];
#pragma unroll
    for (int ql = 0; ql < 4; ++ql) {
        int q = qbase + ql;
        int b = q >> 13;
        int pbase = (b << 12);
        int ci = ((int)cidx[q]) & 4095;
        size_t fcb = ((size_t)(pbase + ci)) << 6;
        float c0, c1 = 0.0f;
        if (f32) {
            const float* ff = (const float*)feat;
            c0 = ff[fcb + lane];
#pragma unroll
            for (int k = 1; k < 16; ++k)
                c1 += wbuf[wv][ql][k] * ff[(((size_t)(pbase + jbuf[wv][ql][k])) << 6) + lane];
        } else {
            const u16* fb = (const u16*)feat;
            c0 = bf(fb[fcb + lane]);
#pragma unroll
            for (int k = 1; k < 16; ++k)
                c1 += wbuf[wv][ql][k] * bf(fb[(((size_t)(pbase + jbuf[wv][ql][k])) << 6) + lane]);
        }
        cf[ql] = c0; co[ql] = c1;
    }

    float wa[4][6], scr[4], ofr[4];
#pragma unroll
    for (int r = 0; r < 4; ++r) {
        int ch = lane + (r << 6);
#pragma unroll
        for (int c = 0; c < 6; ++c) wa[r][c] = w2at[c][ch];
        scr[r] = sc2[ch]; ofr[r] = of2[ch];
    }
    float hv[4][4];
#pragma unroll
    for (int ql = 0; ql < 4; ++ql)
#pragma unroll
        for (int r = 0; r < 4; ++r) hv[ql][r] = 0.0f;
#pragma unroll
    for (int k = 1; k < 16; ++k) {
#pragma unroll
        for (int ql = 0; ql < 4; ++ql) {
            float p0 = dpb[wv][ql][k][0], p1 = dpb[wv][ql][k][1], p2 = dpb[wv][ql][k][2];
            float p3 = dpb[wv][ql][k][3], p4 = dpb[wv][ql][k][4], p5 = dpb[wv][ql][k][5];
            float wk = wbuf[wv][ql][k];
#pragma unroll
            for (int r = 0; r < 4; ++r) {
                float z = p0*wa[r][0] + p1*wa[r][1] + p2*wa[r][2]
                        + p3*wa[r][3] + p4*wa[r][4] + p5*wa[r][5];
                z = z * scr[r] + ofr[r];
                z = fmaxf(z, 0.0f);
                hv[ql][r] += wk * z;
            }
        }
    }
#pragma unroll
    for (int ql = 0; ql < 4; ++ql)
#pragma unroll
        for (int r = 0; r < 4; ++r) hb[wv][ql][lane + (r << 6)] = hv[ql][r];
    __syncthreads();

    float acc[4];
#pragma unroll
    for (int ql = 0; ql < 4; ++ql) acc[ql] = b2bf[lane] * wsb[wv][ql];
    {
        const float4* wrow = reinterpret_cast<const float4*>(canon + (lane << 8));
#pragma unroll 4
        for (int i = 0; i < 64; ++i) {
            float4 w = wrow[i];
#pragma unroll
            for (int ql = 0; ql < 4; ++ql) {
                const float4* hrow = reinterpret_cast<const float4*>(&hb[wv][ql][0]);
                float4 h = hrow[i];
                acc[ql] += w.x*h.x + w.y*h.y + w.z*h.z + w.w*h.w;
            }
        }
    }
#pragma unroll
    for (int ql = 0; ql < 4; ++ql) {
        dfs[wv][ql][lane]       = cf[ql];
        dfs[wv][ql][64 + lane]  = co[ql];
        dfs[wv][ql][128 + lane] = acc[ql];
    }
    __syncthreads();

    float acc1[4] = {0.0f, 0.0f, 0.0f, 0.0f};
    {
        const float4* wr = reinterpret_cast<const float4*>(canon + 16384 + lane * 192);
#pragma unroll 4
        for (int i = 0; i < 48; ++i) {
            float4 w = wr[i];
#pragma unroll
            for (int ql = 0; ql < 4; ++ql) {
                const float4* dv = reinterpret_cast<const float4*>(&dfs[wv][ql][0]);
                float4 a = dv[i];
                acc1[ql] += w.x*a.x + w.y*a.y + w.z*a.z + w.w*a.w;
            }
        }
    }
#pragma unroll
    for (int ql = 0; ql < 4; ++ql) {
        float z1 = acc1[ql] * s1[lane] + o1[lane];
        z1 = fmaxf(z1, 0.0f);
        h1s[wv][ql][lane] = z1;
    }
    __syncthreads();

    float a2[4];
#pragma unroll
    for (int ql = 0; ql < 4; ++ql) a2[ql] = b1f[lane];
    {
        const float4* wr2 = reinterpret_cast<const float4*>(canon + 28672 + (lane << 6));
#pragma unroll
        for (int i = 0; i < 16; ++i) {
            float4 w = wr2[i];
#pragma unroll
            for (int ql = 0; ql < 4; ++ql) {
                const float4* hv2 = reinterpret_cast<const float4*>(&h1s[wv][ql][0]);
                float4 a = hv2[i];
                a2[ql] += w.x*a.x + w.y*a.y + w.z*a.z + w.w*a.w;
            }
        }
    }
#pragma unroll
    for (int ql = 0; ql < 4; ++ql) {
        size_t ob = ((size_t)(qbase + ql) << 6) + lane;
        if (f32) ((float*)outp)[ob] = a2[ql];
        else     ((u16*)outp)[ob]   = f2bf(a2[ql]);
    }
}

extern "C" void kernel_launch(void* const* d_in, const int* in_sizes, int n_in,
                              void* d_out, int out_size, void* d_ws, size_t ws_size,
                              hipStream_t stream) {
    const void* pcl   = d_in[0];
    const void* noise = d_in[1];
    const void* feat  = d_in[2];
    const void* w2a   = d_in[3];
    const void* b2a   = d_in[4];
    const void* g2a   = d_in[5];
    const void* bt2a  = d_in[6];
    const void* w2b   = d_in[7];
    const void* b2b   = d_in[8];
    const void* w1a   = d_in[9];
    const void* b1a   = d_in[10];
    const void* g1a   = d_in[11];
    const void* bt1a  = d_in[12];
    const void* w1b   = d_in[13];
    const void* b1b   = d_in[14];

    char* ws = (char*)d_ws;
    float4* pcl4 = (float4*)ws;                    // 128 KB: [B,M] x (x,y,z,sumsq)
    u16* cidx = (u16*)(ws + 131072);               // 32 KB: [B,N]
    u16* knn  = (u16*)(ws + 163840);               // 256 KB: [B,M,16]
    float* canon = (float*)(ws + 425984);          // 128 KB: fp32 w2b|w1a|w1b
    // total workspace: 557,056 bytes

    k_canon<<<128,  256, 0, stream>>>(noise, w2b, w1a, w1b, canon);
    k_prep <<<32,   256, 0, stream>>>(noise, pcl, pcl4);
    k_close<<<1024, 256, 0, stream>>>(pcl4, noise, cidx);
    k_knnh <<<2048, 256, 0, stream>>>(pcl4, knn);
    k_tail <<<1024, 256, 0, stream>>>(pcl4, noise, feat, cidx, knn,
                                      w2a, b2a, g2a, bt2a, canon, b2b,
                                      b1a, g1a, bt1a, b1b, d_out);
}

// Round 13
// 361.355 us; speedup vs baseline: 1.1205x; 1.0546x over previous
//
#include <hip/hip_runtime.h>
#include <float.h>

typedef unsigned short u16;
typedef unsigned int u32;
typedef unsigned char u8;

// B=2, N=8192, M=4096, C=64, K=16, HID=256
__device__ __forceinline__ float bf(u16 u) { return __uint_as_float(((u32)u) << 16); }
__device__ __forceinline__ u16 f2bf(float v) {
    u32 x = __float_as_uint(v);
    u32 r = x + 0x7fffu + ((x >> 16) & 1u);
    return (u16)(r >> 16);
}
// Dtype probe on EVEN u16 positions of a large ~N(0,1) buffer (pcl_noise).
__device__ __forceinline__ int detect_f32(const void* probe) {
    const u16* u = (const u16*)probe;
    u16 v = u[(threadIdx.x & 63) * 2];
    int e = (int)((v >> 7) & 0xFF);
    int moderate = (e >= 100) && (e <= 140);
    return __popcll(__ballot(moderate)) < 48;   // few moderate -> fp32
}
__device__ __forceinline__ float ldv(int f32, const void* p, int i) {
    return f32 ? ((const float*)p)[i] : bf(((const u16*)p)[i]);
}
// fma-chain dot (matches the validated selection math from the passing rounds).
__device__ __forceinline__ float dot3(float x0, float x1, float x2,
                                      float y0, float y1, float y2) {
    return __fmaf_rn(x2, y2, __fmaf_rn(x1, y1, __fmul_rn(x0, y0)));
}
// Monotonic u32 key: ordering on keys == ordering on float distances.
__device__ __forceinline__ u32 mkey32(float d) {
    u32 f = __float_as_uint(d);
    return f ^ (u32)((((int)f) >> 31) | 0x80000000);
}

// ---- canon: w2b | w1a | w1b as FP32 table (dtype-normalized, full precision) ----
__global__ __launch_bounds__(256) void k_canon(const void* __restrict__ probe,
                                               const void* __restrict__ w2b,
                                               const void* __restrict__ w1a,
                                               const void* __restrict__ w1b,
                                               float* __restrict__ canon) {
    int f32 = detect_f32(probe);
    int ix = blockIdx.x * 256 + threadIdx.x;       // 0..32767
    const void* src; int j;
    if (ix < 16384)      { src = w2b; j = ix; }          // 64x256
    else if (ix < 28672) { src = w1a; j = ix - 16384; }  // 64x192
    else                 { src = w1b; j = ix - 28672; }  // 64x64
    canon[ix] = ldv(f32, src, j);
}

// ---- prep: pcl -> float4 (x,y,z,sumsq) ----
__global__ __launch_bounds__(256) void k_prep(const void* __restrict__ probe,
                                              const void* __restrict__ pcl,
                                              float4* __restrict__ pcl4) {
    int f32 = detect_f32(probe);
    int i = blockIdx.x * 256 + threadIdx.x;        // 0..8191
    float x = ldv(f32, pcl, i*3+0), y = ldv(f32, pcl, i*3+1), z = ldv(f32, pcl, i*3+2);
    float s = __fadd_rn(__fadd_rn(__fmul_rn(x,x), __fmul_rn(y,y)), __fmul_rn(z,z));
    pcl4[i] = make_float4(x, y, z, s);
}

// ---- argmin over M for each noise point; 16 lanes per query; 32 KB chunked tile ----
__global__ __launch_bounds__(256) void k_close(const float4* __restrict__ pcl4,
                                               const void* __restrict__ noise,
                                               u16* __restrict__ cidx) {
    __shared__ __align__(16) float4 tile[2048];
    int f32 = detect_f32(noise);
    int t = threadIdx.x, g = t >> 4, s = t & 15;
    int q = blockIdx.x * 16 + g;                   // global noise-point id
    int b = q >> 13;
    const float4* src = pcl4 + ((size_t)b << 12);
    float x0 = ldv(f32, noise, q*3+0), x1 = ldv(f32, noise, q*3+1), x2 = ldv(f32, noise, q*3+2);
    float sx = __fadd_rn(__fadd_rn(__fmul_rn(x0,x0), __fmul_rn(x1,x1)), __fmul_rn(x2,x2));
    float bd = FLT_MAX; int bi = 0;
    for (int ch = 0; ch < 2; ++ch) {
        __syncthreads();
#pragma unroll
        for (int i = 0; i < 8; ++i) { int ix = t + (i << 8); tile[ix] = src[(ch << 11) + ix]; }
        __syncthreads();
        for (int j = 0; j < 128; ++j) {
            int cl = (j << 4) + s;                 // lane-interleaved: conflict-free LDS
            float4 p = tile[cl];
            float dot = dot3(x0, x1, x2, p.x, p.y, p.z);
            float d = __fadd_rn(__fsub_rn(sx, __fmul_rn(2.0f, dot)), p.w);
            int c = (ch << 11) + cl;               // strictly increasing within thread
            if (d < bd) { bd = d; bi = c; }        // -> first-min on ties
        }
    }
#pragma unroll
    for (int m = 8; m >= 1; m >>= 1) {             // lexicographic (d, idx) merge
        float od = __shfl_xor(bd, m);
        int   oi = __shfl_xor(bi, m);
        if (od < bd || (od == bd && oi < bi)) { bd = od; bi = oi; }
    }
    if (s == 0) cidx[q] = (u16)(bi & 4095);        // masked
}

// ---- k_knnh: exact top-16 via monotone histogram radix-select; 1 wave/query ----
// v2: (a) clamp-bin 255 never counted (kills the 64-way same-address atomic
// serialization); (b) per-candidate bin cached in LDS u8 so the gather pass
// reads LDS instead of re-scanning global; survivors (~30) reload exact d.
// Binning is monotone in d -> {bin<=b*} provably contains the true top-16;
// survivor selection uses exact lex-(key,idx) rank (np-stable order).
__global__ __launch_bounds__(256) void k_knnh(const float4* __restrict__ pcl4,
                                              u16* __restrict__ knn) {
    __shared__ u8  bins[4][4096];                  // 16 KB: per-candidate bin cache
    __shared__ u32 hist[4][256];                   // 4 KB
    __shared__ u32 skey[4][256];                   // 4 KB survivors
    __shared__ u16 sidx[4][256];                   // 2 KB
    __shared__ u32 scnt[4];
    int t = threadIdx.x, lane = t & 63, wv = t >> 6;
    int q = blockIdx.x * 4 + wv;                   // 0..8191
    int b = q >> 12;
    const float4* src = pcl4 + ((size_t)b << 12);
    float4 Q = src[q & 4095];
    float x0 = Q.x, x1 = Q.y, x2 = Q.z, sx = Q.w;
    // zero hist (per wave), cursor
    for (int i = lane; i < 256; i += 64) hist[wv][i] = 0;
    if (lane == 0) scnt[wv] = 0;
    // sample pass: 64 candidates -> scale estimate (any scale is exact)
    float dmn, dmx;
    {
        float4 p = src[lane];
        float dot = dot3(x0, x1, x2, p.x, p.y, p.z);
        float d = __fadd_rn(__fsub_rn(sx, __fmul_rn(2.0f, dot)), p.w);
        dmn = d; dmx = d;
#pragma unroll
        for (int m = 32; m >= 1; m >>= 1) {
            dmn = fminf(dmn, __shfl_xor(dmn, m));
            dmx = fmaxf(dmx, __shfl_xor(dmx, m));
        }
    }
    float sc = 1024.0f / fmaxf(dmx - dmn, 1e-20f); // fine bins over lowest quarter
    __syncthreads();
    // hist pass: bin every candidate, cache bin, count only bins < 255
#pragma unroll 4
    for (int j = 0; j < 64; ++j) {
        int cin = (j << 6) + lane;
        float4 p = src[cin];
        float dot = dot3(x0, x1, x2, p.x, p.y, p.z);
        float d = __fadd_rn(__fsub_rn(sx, __fmul_rn(2.0f, dot)), p.w);
        float fb = fminf(fmaxf((d - dmn) * sc, 0.0f), 255.0f);
        int bn = (int)fb;
        bins[wv][cin] = (u8)bn;
        if (bn < 255) atomicAdd(&hist[wv][bn], 1u); // clamp bin excluded: no hot-spot
    }
    __syncthreads();
    // prefix over bins 0..254 (4/lane) -> first bin with cum >= 16
    int bstar;
    {
        u32 c0 = hist[wv][4*lane], c1 = hist[wv][4*lane+1];
        u32 c2 = hist[wv][4*lane+2], c3 = hist[wv][4*lane+3];
        u32 loc = c0 + c1 + c2 + c3;
        u32 x = loc;
#pragma unroll
        for (int off = 1; off < 64; off <<= 1) { u32 v = __shfl_up(x, off); if (lane >= off) x += v; }
        u32 excl = x - loc;
        int cand = 999;                            // 999 -> everything survives -> fallback
        if (excl + c0 >= 16u) cand = 4*lane;
        else if (excl + c0 + c1 >= 16u) cand = 4*lane + 1;
        else if (excl + c0 + c1 + c2 >= 16u) cand = 4*lane + 2;
        else if (excl + loc >= 16u) cand = 4*lane + 3;
#pragma unroll
        for (int m = 32; m >= 1; m >>= 1) cand = min(cand, __shfl_xor(cand, m));
        bstar = cand;
    }
    // gather pass: survivors from the LDS bin cache; reload exact d only for them
    for (int j = 0; j < 64; ++j) {
        int cin = (j << 6) + lane;
        int bn = (int)bins[wv][cin];
        if (bn <= bstar) {
            u32 pos = atomicAdd(&scnt[wv], 1u);
            if (pos < 256u) {
                float4 p = src[cin];
                float dot = dot3(x0, x1, x2, p.x, p.y, p.z);
                float d = __fadd_rn(__fsub_rn(sx, __fmul_rn(2.0f, dot)), p.w);
                skey[wv][pos] = mkey32(d);
                sidx[wv][pos] = (u16)cin;
            }
        }
    }
    __syncthreads();
    u32 n = scnt[wv];
    if (n <= 256u) {
        // rank-select: rank = #survivors lex-(key,idx)-smaller; rank<16 -> output
        for (u32 e = (u32)lane; e < n; e += 64u) {
            u32 k = skey[wv][e]; u32 i = (u32)sidx[wv][e];
            int rank = 0;
            for (u32 j = 0; j < n; ++j) {
                u32 kj = skey[wv][j]; u32 ij = (u32)sidx[wv][j];
                rank += (kj < k) || (kj == k && ij < i);
            }
            if (rank < 16) knn[((size_t)q << 4) + rank] = (u16)i;
        }
    } else {
        // exact brute-force fallback (validated ripple + shift-register tournament)
        u32 k0=~0u,k1=~0u,k2=~0u,k3=~0u,k4=~0u,k5=~0u,k6=~0u,k7=~0u,
            k8=~0u,k9=~0u,k10=~0u,k11=~0u,k12=~0u,k13=~0u,k14=~0u,k15=~0u;
        u32 i0r=0,i1r=0,i2r=0,i3r=0,i4r=0,i5r=0,i6r=0,i7r=0,
            i8r=0,i9r=0,i10r=0,i11r=0,i12r=0,i13r=0,i14r=0,i15r=0;
        for (int j = 0; j < 64; ++j) {
            int cin = (j << 6) + lane;             // ascending per lane -> stable ties
            float4 p = src[cin];
            float dot = dot3(x0, x1, x2, p.x, p.y, p.z);
            float d = __fadd_rn(__fsub_rn(sx, __fmul_rn(2.0f, dot)), p.w);
            u32 v = mkey32(d); u32 vi = (u32)cin;
            if (v < k15) {
                { u32 c_=(v<k0); u32 nk=c_?v:k0; u32 nv=c_?k0:v; u32 ni=c_?vi:i0r; u32 nj=c_?i0r:vi; k0=nk;i0r=ni;v=nv;vi=nj; }
                { u32 c_=(v<k1); u32 nk=c_?v:k1; u32 nv=c_?k1:v; u32 ni=c_?vi:i1r; u32 nj=c_?i1r:vi; k1=nk;i1r=ni;v=nv;vi=nj; }
                { u32 c_=(v<k2); u32 nk=c_?v:k2; u32 nv=c_?k2:v; u32 ni=c_?vi:i2r; u32 nj=c_?i2r:vi; k2=nk;i2r=ni;v=nv;vi=nj; }
                { u32 c_=(v<k3); u32 nk=c_?v:k3; u32 nv=c_?k3:v; u32 ni=c_?vi:i3r; u32 nj=c_?i3r:vi; k3=nk;i3r=ni;v=nv;vi=nj; }
                { u32 c_=(v<k4); u32 nk=c_?v:k4; u32 nv=c_?k4:v; u32 ni=c_?vi:i4r; u32 nj=c_?i4r:vi; k4=nk;i4r=ni;v=nv;vi=nj; }
                { u32 c_=(v<k5); u32 nk=c_?v:k5; u32 nv=c_?k5:v; u32 ni=c_?vi:i5r; u32 nj=c_?i5r:vi; k5=nk;i5r=ni;v=nv;vi=nj; }
                { u32 c_=(v<k6); u32 nk=c_?v:k6; u32 nv=c_?k6:v; u32 ni=c_?vi:i6r; u32 nj=c_?i6r:vi; k6=nk;i6r=ni;v=nv;vi=nj; }
                { u32 c_=(v<k7); u32 nk=c_?v:k7; u32 nv=c_?k7:v; u32 ni=c_?vi:i7r; u32 nj=c_?i7r:vi; k7=nk;i7r=ni;v=nv;vi=nj; }
                { u32 c_=(v<k8); u32 nk=c_?v:k8; u32 nv=c_?k8:v; u32 ni=c_?vi:i8r; u32 nj=c_?i8r:vi; k8=nk;i8r=ni;v=nv;vi=nj; }
                { u32 c_=(v<k9); u32 nk=c_?v:k9; u32 nv=c_?k9:v; u32 ni=c_?vi:i9r; u32 nj=c_?i9r:vi; k9=nk;i9r=ni;v=nv;vi=nj; }
                { u32 c_=(v<k10); u32 nk=c_?v:k10; u32 nv=c_?k10:v; u32 ni=c_?vi:i10r; u32 nj=c_?i10r:vi; k10=nk;i10r=ni;v=nv;vi=nj; }
                { u32 c_=(v<k11); u32 nk=c_?v:k11; u32 nv=c_?k11:v; u32 ni=c_?vi:i11r; u32 nj=c_?i11r:vi; k11=nk;i11r=ni;v=nv;vi=nj; }
                { u32 c_=(v<k12); u32 nk=c_?v:k12; u32 nv=c_?k12:v; u32 ni=c_?vi:i12r; u32 nj=c_?i12r:vi; k12=nk;i12r=ni;v=nv;vi=nj; }
                { u32 c_=(v<k13); u32 nk=c_?v:k13; u32 nv=c_?k13:v; u32 ni=c_?vi:i13r; u32 nj=c_?i13r:vi; k13=nk;i13r=ni;v=nv;vi=nj; }
                { u32 c_=(v<k14); u32 nk=c_?v:k14; u32 nv=c_?k14:v; u32 ni=c_?vi:i14r; u32 nj=c_?i14r:vi; k14=nk;i14r=ni;v=nv;vi=nj; }
                { u32 c_=(v<k15); u32 nk=c_?v:k15; u32 nv=c_?k15:v; u32 ni=c_?vi:i15r; u32 nj=c_?i15r:vi; k15=nk;i15r=ni;v=nv;vi=nj; }
            }
        }
        u32 myres = 0;
        for (int o = 0; o < 16; ++o) {
            u32 bk = k0, bi2 = i0r;
#pragma unroll
            for (int m = 32; m >= 1; m >>= 1) {
                u32 ok = __shfl_xor(bk, m), oi = __shfl_xor(bi2, m);
                if (ok < bk || (ok == bk && oi < bi2)) { bk = ok; bi2 = oi; }
            }
            if (lane == o) myres = bi2;
            if (k0 == bk && i0r == bi2) {          // winner lane pops its head
                k0=k1; i0r=i1r; k1=k2; i1r=i2r; k2=k3; i2r=i3r; k3=k4; i3r=i4r;
                k4=k5; i4r=i5r; k5=k6; i5r=i6r; k6=k7; i6r=i7r; k7=k8; i7r=i8r;
                k8=k9; i8r=i9r; k9=k10; i9r=i10r; k10=k11; i10r=i11r; k11=k12; i11r=i12r;
                k12=k13; i12r=i13r; k13=k14; i13r=i14r; k14=k15; i14r=i15r;
                k15=~0u; i15r=0xFFFFu;
            }
        }
        if (lane < 16) knn[((size_t)q << 4) + lane] = (u16)myres;
    }
}

// ---- fused tail: 4 queries per wave (weight-load amortization), 16 per block ----
__global__ __launch_bounds__(256) void k_tail(const float4* __restrict__ pcl4,
                                              const void* __restrict__ noise,
                                              const void* __restrict__ feat,
                                              const u16* __restrict__ cidx,
                                              const u16* __restrict__ knn,
                                              const void* __restrict__ w2a,
                                              const void* __restrict__ b2a,
                                              const void* __restrict__ g2a,
                                              const void* __restrict__ bt2a,
                                              const float* __restrict__ canon,
                                              const void* __restrict__ b2b,
                                              const void* __restrict__ b1a,
                                              const void* __restrict__ g1a,
                                              const void* __restrict__ bt1a,
                                              const void* __restrict__ b1b,
                                              void* __restrict__ outp) {
    __shared__ float w2at[6][256];
    __shared__ float sc2[256], of2[256];
    __shared__ float b2bf[64], s1[64], o1[64], b1f[64];
    __shared__ __align__(16) float hb[4][4][256];
    __shared__ __align__(16) float dfs[4][4][192];
    __shared__ __align__(16) float h1s[4][4][64];
    __shared__ float dpb[4][4][16][6];
    __shared__ float wbuf[4][4][16];
    __shared__ int   jbuf[4][4][16];
    __shared__ float wsb[4][4];

    int f32 = detect_f32(noise);
    int t = threadIdx.x;
    {
        float s2 = ldv(f32, g2a, t) / sqrtf(1.0f + 1e-5f);
        sc2[t] = s2;
        of2[t] = ldv(f32, b2a, t) * s2 + ldv(f32, bt2a, t);
#pragma unroll
        for (int c = 0; c < 6; ++c) w2at[c][t] = ldv(f32, w2a, t*6+c);
        if (t < 64) {
            b2bf[t] = ldv(f32, b2b, t);
            float s = ldv(f32, g1a, t) / sqrtf(1.0f + 1e-5f);
            s1[t] = s; o1[t] = ldv(f32, b1a, t) * s + ldv(f32, bt1a, t); b1f[t] = ldv(f32, b1b, t);
        }
    }
    int lane = t & 63, wv = t >> 6;
    int qbase = blockIdx.x * 16 + wv * 4;
    {
        int ql = lane >> 4, s = lane & 15;
        int q = qbase + ql;
        int b = q >> 13;
        int pbase = (b << 12);
        int ci = ((int)cidx[q]) & 4095;
        float4 cp = pcl4[pbase + ci];
        float x0 = ldv(f32, noise, q*3+0), x1 = ldv(f32, noise, q*3+1), x2 = ldv(f32, noise, q*3+2);
        float e = 0.0f;
        if (s >= 1) {
            int jk = ((int)knn[(size_t)(pbase + ci) * 16 + s]) & 4095;
            float4 p = pcl4[pbase + jk];
            float d0 = p.x - x0, d1 = p.y - x1, d2 = p.z - x2;
            float dst = sqrtf(__fadd_rn(__fadd_rn(__fmul_rn(d0,d0), __fmul_rn(d1,d1)), __fmul_rn(d2,d2)));
            e = expf(-10.0f * dst);
            dpb[wv][ql][s][0] = d0; dpb[wv][ql][s][1] = d1; dpb[wv][ql][s][2] = d2;
            dpb[wv][ql][s][3] = cp.x; dpb[wv][ql][s][4] = cp.y; dpb[wv][ql][s][5] = cp.z;
            jbuf[wv][ql][s] = jk;
        }
        float es = e;
#pragma unroll
        for (int m = 8; m >= 1; m >>= 1) es += __shfl_xor(es, m, 16);
        float den = es + 1e-7f;
        if (s >= 1) wbuf[wv][ql][s] = e / den;
        if (s == 0) wsb[wv][ql] = es / den;
    }
    __syncthreads();

    float cf[4], co[4];
#pragma unroll
    for (int ql = 0; ql < 4; ++ql) {
        int q = qbase + ql;
        int b = q >> 13;
        int pbase = (b << 12);
        int ci = ((int)cidx[q]) & 4095;
        size_t fcb = ((size_t)(pbase + ci)) << 6;
        float c0, c1 = 0.0f;
        if (f32) {
            const float* ff = (const float*)feat;
            c0 = ff[fcb + lane];
#pragma unroll
            for (int k = 1; k < 16; ++k)
                c1 += wbuf[wv][ql][k] * ff[(((size_t)(pbase + jbuf[wv][ql][k])) << 6) + lane];
        } else {
            const u16* fb = (const u16*)feat;
            c0 = bf(fb[fcb + lane]);
#pragma unroll
            for (int k = 1; k < 16; ++k)
                c1 += wbuf[wv][ql][k] * bf(fb[(((size_t)(pbase + jbuf[wv][ql][k])) << 6) + lane]);
        }
        cf[ql] = c0; co[ql] = c1;
    }

    float wa[4][6], scr[4], ofr[4];
#pragma unroll
    for (int r = 0; r < 4; ++r) {
        int ch = lane + (r << 6);
#pragma unroll
        for (int c = 0; c < 6; ++c) wa[r][c] = w2at[c][ch];
        scr[r] = sc2[ch]; ofr[r] = of2[ch];
    }
    float hv[4][4];
#pragma unroll
    for (int ql = 0; ql < 4; ++ql)
#pragma unroll
        for (int r = 0; r < 4; ++r) hv[ql][r] = 0.0f;
#pragma unroll
    for (int k = 1; k < 16; ++k) {
#pragma unroll
        for (int ql = 0; ql < 4; ++ql) {
            float p0 = dpb[wv][ql][k][0], p1 = dpb[wv][ql][k][1], p2 = dpb[wv][ql][k][2];
            float p3 = dpb[wv][ql][k][3], p4 = dpb[wv][ql][k][4], p5 = dpb[wv][ql][k][5];
            float wk = wbuf[wv][ql][k];
#pragma unroll
            for (int r = 0; r < 4; ++r) {
                float z = p0*wa[r][0] + p1*wa[r][1] + p2*wa[r][2]
                        + p3*wa[r][3] + p4*wa[r][4] + p5*wa[r][5];
                z = z * scr[r] + ofr[r];
                z = fmaxf(z, 0.0f);
                hv[ql][r] += wk * z;
            }
        }
    }
#pragma unroll
    for (int ql = 0; ql < 4; ++ql)
#pragma unroll
        for (int r = 0; r < 4; ++r) hb[wv][ql][lane + (r << 6)] = hv[ql][r];
    __syncthreads();

    float acc[4];
#pragma unroll
    for (int ql = 0; ql < 4; ++ql) acc[ql] = b2bf[lane] * wsb[wv][ql];
    {
        const float4* wrow = reinterpret_cast<const float4*>(canon + (lane << 8));
#pragma unroll 4
        for (int i = 0; i < 64; ++i) {
            float4 w = wrow[i];
#pragma unroll
            for (int ql = 0; ql < 4; ++ql) {
                const float4* hrow = reinterpret_cast<const float4*>(&hb[wv][ql][0]);
                float4 h = hrow[i];
                acc[ql] += w.x*h.x + w.y*h.y + w.z*h.z + w.w*h.w;
            }
        }
    }
#pragma unroll
    for (int ql = 0; ql < 4; ++ql) {
        dfs[wv][ql][lane]       = cf[ql];
        dfs[wv][ql][64 + lane]  = co[ql];
        dfs[wv][ql][128 + lane] = acc[ql];
    }
    __syncthreads();

    float acc1[4] = {0.0f, 0.0f, 0.0f, 0.0f};
    {
        const float4* wr = reinterpret_cast<const float4*>(canon + 16384 + lane * 192);
#pragma unroll 4
        for (int i = 0; i < 48; ++i) {
            float4 w = wr[i];
#pragma unroll
            for (int ql = 0; ql < 4; ++ql) {
                const float4* dv = reinterpret_cast<const float4*>(&dfs[wv][ql][0]);
                float4 a = dv[i];
                acc1[ql] += w.x*a.x + w.y*a.y + w.z*a.z + w.w*a.w;
            }
        }
    }
#pragma unroll
    for (int ql = 0; ql < 4; ++ql) {
        float z1 = acc1[ql] * s1[lane] + o1[lane];
        z1 = fmaxf(z1, 0.0f);
        h1s[wv][ql][lane] = z1;
    }
    __syncthreads();

    float a2[4];
#pragma unroll
    for (int ql = 0; ql < 4; ++ql) a2[ql] = b1f[lane];
    {
        const float4* wr2 = reinterpret_cast<const float4*>(canon + 28672 + (lane << 6));
#pragma unroll
        for (int i = 0; i < 16; ++i) {
            float4 w = wr2[i];
#pragma unroll
            for (int ql = 0; ql < 4; ++ql) {
                const float4* hv2 = reinterpret_cast<const float4*>(&h1s[wv][ql][0]);
                float4 a = hv2[i];
                a2[ql] += w.x*a.x + w.y*a.y + w.z*a.z + w.w*a.w;
            }
        }
    }
#pragma unroll
    for (int ql = 0; ql < 4; ++ql) {
        size_t ob = ((size_t)(qbase + ql) << 6) + lane;
        if (f32) ((float*)outp)[ob] = a2[ql];
        else     ((u16*)outp)[ob]   = f2bf(a2[ql]);
    }
}

extern "C" void kernel_launch(void* const* d_in, const int* in_sizes, int n_in,
                              void* d_out, int out_size, void* d_ws, size_t ws_size,
                              hipStream_t stream) {
    const void* pcl   = d_in[0];
    const void* noise = d_in[1];
    const void* feat  = d_in[2];
    const void* w2a   = d_in[3];
    const void* b2a   = d_in[4];
    const void* g2a   = d_in[5];
    const void* bt2a  = d_in[6];
    const void* w2b   = d_in[7];
    const void* b2b   = d_in[8];
    const void* w1a   = d_in[9];
    const void* b1a   = d_in[10];
    const void* g1a   = d_in[11];
    const void* bt1a  = d_in[12];
    const void* w1b   = d_in[13];
    const void* b1b   = d_in[14];

    char* ws = (char*)d_ws;
    float4* pcl4 = (float4*)ws;                    // 128 KB: [B,M] x (x,y,z,sumsq)
    u16* cidx = (u16*)(ws + 131072);               // 32 KB: [B,N]
    u16* knn  = (u16*)(ws + 163840);               // 256 KB: [B,M,16]
    float* canon = (float*)(ws + 425984);          // 128 KB: fp32 w2b|w1a|w1b
    // total workspace: 557,056 bytes

    k_canon<<<128,  256, 0, stream>>>(noise, w2b, w1a, w1b, canon);
    k_prep <<<32,   256, 0, stream>>>(noise, pcl, pcl4);
    k_close<<<1024, 256, 0, stream>>>(pcl4, noise, cidx);
    k_knnh <<<2048, 256, 0, stream>>>(pcl4, knn);
    k_tail <<<1024, 256, 0, stream>>>(pcl4, noise, feat, cidx, knn,
                                      w2a, b2a, g2a, bt2a, canon, b2b,
                                      b1a, g1a, bt1a, b1b, d_out);
}

// Round 14
// 255.415 us; speedup vs baseline: 1.5852x; 1.4148x over previous
//
#include <hip/hip_runtime.h>
#include <float.h>

typedef unsigned short u16;
typedef unsigned int u32;
typedef unsigned char u8;

// B=2, N=8192, M=4096, C=64, K=16, HID=256
__device__ __forceinline__ float bf(u16 u) { return __uint_as_float(((u32)u) << 16); }
__device__ __forceinline__ u16 f2bf(float v) {
    u32 x = __float_as_uint(v);
    u32 r = x + 0x7fffu + ((x >> 16) & 1u);
    return (u16)(r >> 16);
}
// Dtype probe on EVEN u16 positions of a large ~N(0,1) buffer (pcl_noise).
__device__ __forceinline__ int detect_f32(const void* probe) {
    const u16* u = (const u16*)probe;
    u16 v = u[(threadIdx.x & 63) * 2];
    int e = (int)((v >> 7) & 0xFF);
    int moderate = (e >= 100) && (e <= 140);
    return __popcll(__ballot(moderate)) < 48;   // few moderate -> fp32
}
__device__ __forceinline__ float ldv(int f32, const void* p, int i) {
    return f32 ? ((const float*)p)[i] : bf(((const u16*)p)[i]);
}
// fma-chain dot (matches the validated selection math from the passing rounds).
__device__ __forceinline__ float dot3(float x0, float x1, float x2,
                                      float y0, float y1, float y2) {
    return __fmaf_rn(x2, y2, __fmaf_rn(x1, y1, __fmul_rn(x0, y0)));
}
// Monotonic u32 key: ordering on keys == ordering on float distances.
__device__ __forceinline__ u32 mkey32(float d) {
    u32 f = __float_as_uint(d);
    return f ^ (u32)((((int)f) >> 31) | 0x80000000);
}

// ---- canon: w2b | w1a | w1b as FP32 table (dtype-normalized, full precision) ----
__global__ __launch_bounds__(256) void k_canon(const void* __restrict__ probe,
                                               const void* __restrict__ w2b,
                                               const void* __restrict__ w1a,
                                               const void* __restrict__ w1b,
                                               float* __restrict__ canon) {
    int f32 = detect_f32(probe);
    int ix = blockIdx.x * 256 + threadIdx.x;       // 0..32767
    const void* src; int j;
    if (ix < 16384)      { src = w2b; j = ix; }          // 64x256
    else if (ix < 28672) { src = w1a; j = ix - 16384; }  // 64x192
    else                 { src = w1b; j = ix - 28672; }  // 64x64
    canon[ix] = ldv(f32, src, j);
}

// ---- prep: pcl -> float4 (x,y,z,sumsq) ----
__global__ __launch_bounds__(256) void k_prep(const void* __restrict__ probe,
                                              const void* __restrict__ pcl,
                                              float4* __restrict__ pcl4) {
    int f32 = detect_f32(probe);
    int i = blockIdx.x * 256 + threadIdx.x;        // 0..8191
    float x = ldv(f32, pcl, i*3+0), y = ldv(f32, pcl, i*3+1), z = ldv(f32, pcl, i*3+2);
    float s = __fadd_rn(__fadd_rn(__fmul_rn(x,x), __fmul_rn(y,y)), __fmul_rn(z,z));
    pcl4[i] = make_float4(x, y, z, s);
}

// ---- argmin over M for each noise point; 16 lanes per query; 32 KB chunked tile ----
__global__ __launch_bounds__(256) void k_close(const float4* __restrict__ pcl4,
                                               const void* __restrict__ noise,
                                               u16* __restrict__ cidx) {
    __shared__ __align__(16) float4 tile[2048];
    int f32 = detect_f32(noise);
    int t = threadIdx.x, g = t >> 4, s = t & 15;
    int q = blockIdx.x * 16 + g;                   // global noise-point id
    int b = q >> 13;
    const float4* src = pcl4 + ((size_t)b << 12);
    float x0 = ldv(f32, noise, q*3+0), x1 = ldv(f32, noise, q*3+1), x2 = ldv(f32, noise, q*3+2);
    float sx = __fadd_rn(__fadd_rn(__fmul_rn(x0,x0), __fmul_rn(x1,x1)), __fmul_rn(x2,x2));
    float bd = FLT_MAX; int bi = 0;
    for (int ch = 0; ch < 2; ++ch) {
        __syncthreads();
#pragma unroll
        for (int i = 0; i < 8; ++i) { int ix = t + (i << 8); tile[ix] = src[(ch << 11) + ix]; }
        __syncthreads();
        for (int j = 0; j < 128; ++j) {
            int cl = (j << 4) + s;                 // lane-interleaved: conflict-free LDS
            float4 p = tile[cl];
            float dot = dot3(x0, x1, x2, p.x, p.y, p.z);
            float d = __fadd_rn(__fsub_rn(sx, __fmul_rn(2.0f, dot)), p.w);
            int c = (ch << 11) + cl;               // strictly increasing within thread
            if (d < bd) { bd = d; bi = c; }        // -> first-min on ties
        }
    }
#pragma unroll
    for (int m = 8; m >= 1; m >>= 1) {             // lexicographic (d, idx) merge
        float od = __shfl_xor(bd, m);
        int   oi = __shfl_xor(bi, m);
        if (od < bd || (od == bd && oi < bi)) { bd = od; bi = oi; }
    }
    if (s == 0) cidx[q] = (u16)(bi & 4095);        // masked
}

// ---- k_knnh v4: histogram radix-select, ONE BLOCK (4 waves) per query ----
// 4x more parallelism per query + 4x shorter load chains vs v3 (wave/query).
// Selection math bit-identical: monotone binning (scale only affects balance),
// exact lex-(key,idx) rank-select, wave-0 brute-force fallback if >256 survive.
__global__ __launch_bounds__(256) void k_knnh(const float4* __restrict__ pcl4,
                                              u16* __restrict__ knn) {
    __shared__ u8  bins[4096];                     // 4 KB: per-candidate bin cache
    __shared__ u32 hist[256];                      // 1 KB
    __shared__ u32 skey[256];                      // 1 KB survivors
    __shared__ u16 sidx[256];                      // 0.5 KB
    __shared__ float rmn[4], rmx[4];
    __shared__ u32 scnt;
    __shared__ int ibst;
    int t = threadIdx.x, lane = t & 63, wv = t >> 6;
    int q = blockIdx.x;                            // 0..8191
    int b = q >> 12;
    const float4* src = pcl4 + ((size_t)b << 12);
    float4 Q = src[q & 4095];
    float x0 = Q.x, x1 = Q.y, x2 = Q.z, sx = Q.w;
    if (t < 256) hist[t] = 0;                      // zero hist
    if (t == 0) scnt = 0;
    // sample pass: 256 candidates (stride 16) -> block min/max scale estimate
    {
        float4 p = src[t << 4];
        float dot = dot3(x0, x1, x2, p.x, p.y, p.z);
        float d = __fadd_rn(__fsub_rn(sx, __fmul_rn(2.0f, dot)), p.w);
        float mn = d, mx = d;
#pragma unroll
        for (int m = 32; m >= 1; m >>= 1) {
            mn = fminf(mn, __shfl_xor(mn, m));
            mx = fmaxf(mx, __shfl_xor(mx, m));
        }
        if (lane == 0) { rmn[wv] = mn; rmx[wv] = mx; }
    }
    __syncthreads();
    float dmn = fminf(fminf(rmn[0], rmn[1]), fminf(rmn[2], rmn[3]));
    float dmx = fmaxf(fmaxf(rmx[0], rmx[1]), fmaxf(rmx[2], rmx[3]));
    float sc = 1024.0f / fmaxf(dmx - dmn, 1e-20f); // fine bins over lowest quarter
    // hist pass: 16 candidates/thread, bin cached, clamp-bin 255 never counted
#pragma unroll 4
    for (int j = 0; j < 16; ++j) {
        int cin = (j << 8) + t;
        float4 p = src[cin];
        float dot = dot3(x0, x1, x2, p.x, p.y, p.z);
        float d = __fadd_rn(__fsub_rn(sx, __fmul_rn(2.0f, dot)), p.w);
        float fb = fminf(fmaxf((d - dmn) * sc, 0.0f), 255.0f);
        int bn = (int)fb;
        bins[cin] = (u8)bn;
        if (bn < 255) atomicAdd(&hist[bn], 1u);    // no hot-spot
    }
    __syncthreads();
    // prefix over bins 0..254 by wave 0 -> first bin with cum >= 16
    if (t < 64) {
        u32 c0 = hist[4*lane], c1 = hist[4*lane+1];
        u32 c2 = hist[4*lane+2], c3 = hist[4*lane+3];
        u32 loc = c0 + c1 + c2 + c3;
        u32 x = loc;
#pragma unroll
        for (int off = 1; off < 64; off <<= 1) { u32 v = __shfl_up(x, off); if (lane >= off) x += v; }
        u32 excl = x - loc;
        int cand = 999;                            // 999 -> everything survives -> fallback
        if (excl + c0 >= 16u) cand = 4*lane;
        else if (excl + c0 + c1 >= 16u) cand = 4*lane + 1;
        else if (excl + c0 + c1 + c2 >= 16u) cand = 4*lane + 2;
        else if (excl + loc >= 16u) cand = 4*lane + 3;
#pragma unroll
        for (int m = 32; m >= 1; m >>= 1) cand = min(cand, __shfl_xor(cand, m));
        if (lane == 0) ibst = cand;
    }
    __syncthreads();
    int bstar = ibst;
    // gather pass: survivors from the LDS bin cache; reload exact d only for them
#pragma unroll
    for (int j = 0; j < 16; ++j) {
        int cin = (j << 8) + t;
        if ((int)bins[cin] <= bstar) {
            u32 pos = atomicAdd(&scnt, 1u);
            if (pos < 256u) {
                float4 p = src[cin];
                float dot = dot3(x0, x1, x2, p.x, p.y, p.z);
                float d = __fadd_rn(__fsub_rn(sx, __fmul_rn(2.0f, dot)), p.w);
                skey[pos] = mkey32(d);
                sidx[pos] = (u16)cin;
            }
        }
    }
    __syncthreads();
    u32 n = scnt;
    if (n <= 256u) {
        // rank-select: rank = #survivors lex-(key,idx)-smaller; rank<16 -> output
        for (u32 e = (u32)t; e < n; e += 256u) {
            u32 k = skey[e]; u32 i = (u32)sidx[e];
            int rank = 0;
            for (u32 j = 0; j < n; ++j) {
                u32 kj = skey[j]; u32 ij = (u32)sidx[j];
                rank += (kj < k) || (kj == k && ij < i);
            }
            if (rank < 16) knn[((size_t)q << 4) + rank] = (u16)i;
        }
    } else if (t < 64) {
        // exact brute-force fallback on wave 0 (validated ripple + tournament)
        u32 k0=~0u,k1=~0u,k2=~0u,k3=~0u,k4=~0u,k5=~0u,k6=~0u,k7=~0u,
            k8=~0u,k9=~0u,k10=~0u,k11=~0u,k12=~0u,k13=~0u,k14=~0u,k15=~0u;
        u32 i0r=0,i1r=0,i2r=0,i3r=0,i4r=0,i5r=0,i6r=0,i7r=0,
            i8r=0,i9r=0,i10r=0,i11r=0,i12r=0,i13r=0,i14r=0,i15r=0;
        for (int j = 0; j < 64; ++j) {
            int cin = (j << 6) + lane;             // ascending per lane -> stable ties
            float4 p = src[cin];
            float dot = dot3(x0, x1, x2, p.x, p.y, p.z);
            float d = __fadd_rn(__fsub_rn(sx, __fmul_rn(2.0f, dot)), p.w);
            u32 v = mkey32(d); u32 vi = (u32)cin;
            if (v < k15) {
                { u32 c_=(v<k0); u32 nk=c_?v:k0; u32 nv=c_?k0:v; u32 ni=c_?vi:i0r; u32 nj=c_?i0r:vi; k0=nk;i0r=ni;v=nv;vi=nj; }
                { u32 c_=(v<k1); u32 nk=c_?v:k1; u32 nv=c_?k1:v; u32 ni=c_?vi:i1r; u32 nj=c_?i1r:vi; k1=nk;i1r=ni;v=nv;vi=nj; }
                { u32 c_=(v<k2); u32 nk=c_?v:k2; u32 nv=c_?k2:v; u32 ni=c_?vi:i2r; u32 nj=c_?i2r:vi; k2=nk;i2r=ni;v=nv;vi=nj; }
                { u32 c_=(v<k3); u32 nk=c_?v:k3; u32 nv=c_?k3:v; u32 ni=c_?vi:i3r; u32 nj=c_?i3r:vi; k3=nk;i3r=ni;v=nv;vi=nj; }
                { u32 c_=(v<k4); u32 nk=c_?v:k4; u32 nv=c_?k4:v; u32 ni=c_?vi:i4r; u32 nj=c_?i4r:vi; k4=nk;i4r=ni;v=nv;vi=nj; }
                { u32 c_=(v<k5); u32 nk=c_?v:k5; u32 nv=c_?k5:v; u32 ni=c_?vi:i5r; u32 nj=c_?i5r:vi; k5=nk;i5r=ni;v=nv;vi=nj; }
                { u32 c_=(v<k6); u32 nk=c_?v:k6; u32 nv=c_?k6:v; u32 ni=c_?vi:i6r; u32 nj=c_?i6r:vi; k6=nk;i6r=ni;v=nv;vi=nj; }
                { u32 c_=(v<k7); u32 nk=c_?v:k7; u32 nv=c_?k7:v; u32 ni=c_?vi:i7r; u32 nj=c_?i7r:vi; k7=nk;i7r=ni;v=nv;vi=nj; }
                { u32 c_=(v<k8); u32 nk=c_?v:k8; u32 nv=c_?k8:v; u32 ni=c_?vi:i8r; u32 nj=c_?i8r:vi; k8=nk;i8r=ni;v=nv;vi=nj; }
                { u32 c_=(v<k9); u32 nk=c_?v:k9; u32 nv=c_?k9:v; u32 ni=c_?vi:i9r; u32 nj=c_?i9r:vi; k9=nk;i9r=ni;v=nv;vi=nj; }
                { u32 c_=(v<k10); u32 nk=c_?v:k10; u32 nv=c_?k10:v; u32 ni=c_?vi:i10r; u32 nj=c_?i10r:vi; k10=nk;i10r=ni;v=nv;vi=nj; }
                { u32 c_=(v<k11); u32 nk=c_?v:k11; u32 nv=c_?k11:v; u32 ni=c_?vi:i11r; u32 nj=c_?i11r:vi; k11=nk;i11r=ni;v=nv;vi=nj; }
                { u32 c_=(v<k12); u32 nk=c_?v:k12; u32 nv=c_?k12:v; u32 ni=c_?vi:i12r; u32 nj=c_?i12r:vi; k12=nk;i12r=ni;v=nv;vi=nj; }
                { u32 c_=(v<k13); u32 nk=c_?v:k13; u32 nv=c_?k13:v; u32 ni=c_?vi:i13r; u32 nj=c_?i13r:vi; k13=nk;i13r=ni;v=nv;vi=nj; }
                { u32 c_=(v<k14); u32 nk=c_?v:k14; u32 nv=c_?k14:v; u32 ni=c_?vi:i14r; u32 nj=c_?i14r:vi; k14=nk;i14r=ni;v=nv;vi=nj; }
                { u32 c_=(v<k15); u32 nk=c_?v:k15; u32 nv=c_?k15:v; u32 ni=c_?vi:i15r; u32 nj=c_?i15r:vi; k15=nk;i15r=ni;v=nv;vi=nj; }
            }
        }
        u32 myres = 0;
        for (int o = 0; o < 16; ++o) {
            u32 bk = k0, bi2 = i0r;
#pragma unroll
            for (int m = 32; m >= 1; m >>= 1) {
                u32 ok = __shfl_xor(bk, m), oi = __shfl_xor(bi2, m);
                if (ok < bk || (ok == bk && oi < bi2)) { bk = ok; bi2 = oi; }
            }
            if (lane == o) myres = bi2;
            if (k0 == bk && i0r == bi2) {          // winner lane pops its head
                k0=k1; i0r=i1r; k1=k2; i1r=i2r; k2=k3; i2r=i3r; k3=k4; i3r=i4r;
                k4=k5; i4r=i5r; k5=k6; i5r=i6r; k6=k7; i6r=i7r; k7=k8; i7r=i8r;
                k8=k9; i8r=i9r; k9=k10; i9r=i10r; k10=k11; i10r=i11r; k11=k12; i11r=i12r;
                k12=k13; i12r=i13r; k13=k14; i13r=i14r; k14=k15; i14r=i15r;
                k15=~0u; i15r=0xFFFFu;
            }
        }
        if (lane < 16) knn[((size_t)q << 4) + lane] = (u16)myres;
    }
}

// ---- fused tail: 4 queries per wave (weight-load amortization), 16 per block ----
__global__ __launch_bounds__(256) void k_tail(const float4* __restrict__ pcl4,
                                              const void* __restrict__ noise,
                                              const void* __restrict__ feat,
                                              const u16* __restrict__ cidx,
                                              const u16* __restrict__ knn,
                                              const void* __restrict__ w2a,
                                              const void* __restrict__ b2a,
                                              const void* __restrict__ g2a,
                                              const void* __restrict__ bt2a,
                                              const float* __restrict__ canon,
                                              const void* __restrict__ b2b,
                                              const void* __restrict__ b1a,
                                              const void* __restrict__ g1a,
                                              const void* __restrict__ bt1a,
                                              const void* __restrict__ b1b,
                                              void* __restrict__ outp) {
    __shared__ float w2at[6][256];
    __shared__ float sc2[256], of2[256];
    __shared__ float b2bf[64], s1[64], o1[64], b1f[64];
    __shared__ __align__(16) float hb[4][4][256];
    __shared__ __align__(16) float dfs[4][4][192];
    __shared__ __align__(16) float h1s[4][4][64];
    __shared__ float dpb[4][4][16][6];
    __shared__ float wbuf[4][4][16];
    __shared__ int   jbuf[4][4][16];
    __shared__ float wsb[4][4];

    int f32 = detect_f32(noise);
    int t = threadIdx.x;
    {
        float s2 = ldv(f32, g2a, t) / sqrtf(1.0f + 1e-5f);
        sc2[t] = s2;
        of2[t] = ldv(f32, b2a, t) * s2 + ldv(f32, bt2a, t);
#pragma unroll
        for (int c = 0; c < 6; ++c) w2at[c][t] = ldv(f32, w2a, t*6+c);
        if (t < 64) {
            b2bf[t] = ldv(f32, b2b, t);
            float s = ldv(f32, g1a, t) / sqrtf(1.0f + 1e-5f);
            s1[t] = s; o1[t] = ldv(f32, b1a, t) * s + ldv(f32, bt1a, t); b1f[t] = ldv(f32, b1b, t);
        }
    }
    int lane = t & 63, wv = t >> 6;
    int qbase = blockIdx.x * 16 + wv * 4;
    {
        int ql = lane >> 4, s = lane & 15;
        int q = qbase + ql;
        int b = q >> 13;
        int pbase = (b << 12);
        int ci = ((int)cidx[q]) & 4095;
        float4 cp = pcl4[pbase + ci];
        float x0 = ldv(f32, noise, q*3+0), x1 = ldv(f32, noise, q*3+1), x2 = ldv(f32, noise, q*3+2);
        float e = 0.0f;
        if (s >= 1) {
            int jk = ((int)knn[(size_t)(pbase + ci) * 16 + s]) & 4095;
            float4 p = pcl4[pbase + jk];
            float d0 = p.x - x0, d1 = p.y - x1, d2 = p.z - x2;
            float dst = sqrtf(__fadd_rn(__fadd_rn(__fmul_rn(d0,d0), __fmul_rn(d1,d1)), __fmul_rn(d2,d2)));
            e = expf(-10.0f * dst);
            dpb[wv][ql][s][0] = d0; dpb[wv][ql][s][1] = d1; dpb[wv][ql][s][2] = d2;
            dpb[wv][ql][s][3] = cp.x; dpb[wv][ql][s][4] = cp.y; dpb[wv][ql][s][5] = cp.z;
            jbuf[wv][ql][s] = jk;
        }
        float es = e;
#pragma unroll
        for (int m = 8; m >= 1; m >>= 1) es += __shfl_xor(es, m, 16);
        float den = es + 1e-7f;
        if (s >= 1) wbuf[wv][ql][s] = e / den;
        if (s == 0) wsb[wv][ql] = es / den;
    }
    __syncthreads();

    float cf[4], co[4];
#pragma unroll
    for (int ql = 0; ql < 4; ++ql) {
        int q = qbase + ql;
        int b = q >> 13;
        int pbase = (b << 12);
        int ci = ((int)cidx[q]) & 4095;
        size_t fcb = ((size_t)(pbase + ci)) << 6;
        float c0, c1 = 0.0f;
        if (f32) {
            const float* ff = (const float*)feat;
            c0 = ff[fcb + lane];
#pragma unroll
            for (int k = 1; k < 16; ++k)
                c1 += wbuf[wv][ql][k] * ff[(((size_t)(pbase + jbuf[wv][ql][k])) << 6) + lane];
        } else {
            const u16* fb = (const u16*)feat;
            c0 = bf(fb[fcb + lane]);
#pragma unroll
            for (int k = 1; k < 16; ++k)
                c1 += wbuf[wv][ql][k] * bf(fb[(((size_t)(pbase + jbuf[wv][ql][k])) << 6) + lane]);
        }
        cf[ql] = c0; co[ql] = c1;
    }

    float wa[4][6], scr[4], ofr[4];
#pragma unroll
    for (int r = 0; r < 4; ++r) {
        int ch = lane + (r << 6);
#pragma unroll
        for (int c = 0; c < 6; ++c) wa[r][c] = w2at[c][ch];
        scr[r] = sc2[ch]; ofr[r] = of2[ch];
    }
    float hv[4][4];
#pragma unroll
    for (int ql = 0; ql < 4; ++ql)
#pragma unroll
        for (int r = 0; r < 4; ++r) hv[ql][r] = 0.0f;
#pragma unroll
    for (int k = 1; k < 16; ++k) {
#pragma unroll
        for (int ql = 0; ql < 4; ++ql) {
            float p0 = dpb[wv][ql][k][0], p1 = dpb[wv][ql][k][1], p2 = dpb[wv][ql][k][2];
            float p3 = dpb[wv][ql][k][3], p4 = dpb[wv][ql][k][4], p5 = dpb[wv][ql][k][5];
            float wk = wbuf[wv][ql][k];
#pragma unroll
            for (int r = 0; r < 4; ++r) {
                float z = p0*wa[r][0] + p1*wa[r][1] + p2*wa[r][2]
                        + p3*wa[r][3] + p4*wa[r][4] + p5*wa[r][5];
                z = z * scr[r] + ofr[r];
                z = fmaxf(z, 0.0f);
                hv[ql][r] += wk * z;
            }
        }
    }
#pragma unroll
    for (int ql = 0; ql < 4; ++ql)
#pragma unroll
        for (int r = 0; r < 4; ++r) hb[wv][ql][lane + (r << 6)] = hv[ql][r];
    __syncthreads();

    float acc[4];
#pragma unroll
    for (int ql = 0; ql < 4; ++ql) acc[ql] = b2bf[lane] * wsb[wv][ql];
    {
        const float4* wrow = reinterpret_cast<const float4*>(canon + (lane << 8));
#pragma unroll 4
        for (int i = 0; i < 64; ++i) {
            float4 w = wrow[i];
#pragma unroll
            for (int ql = 0; ql < 4; ++ql) {
                const float4* hrow = reinterpret_cast<const float4*>(&hb[wv][ql][0]);
                float4 h = hrow[i];
                acc[ql] += w.x*h.x + w.y*h.y + w.z*h.z + w.w*h.w;
            }
        }
    }
#pragma unroll
    for (int ql = 0; ql < 4; ++ql) {
        dfs[wv][ql][lane]       = cf[ql];
        dfs[wv][ql][64 + lane]  = co[ql];
        dfs[wv][ql][128 + lane] = acc[ql];
    }
    __syncthreads();

    float acc1[4] = {0.0f, 0.0f, 0.0f, 0.0f};
    {
        const float4* wr = reinterpret_cast<const float4*>(canon + 16384 + lane * 192);
#pragma unroll 4
        for (int i = 0; i < 48; ++i) {
            float4 w = wr[i];
#pragma unroll
            for (int ql = 0; ql < 4; ++ql) {
                const float4* dv = reinterpret_cast<const float4*>(&dfs[wv][ql][0]);
                float4 a = dv[i];
                acc1[ql] += w.x*a.x + w.y*a.y + w.z*a.z + w.w*a.w;
            }
        }
    }
#pragma unroll
    for (int ql = 0; ql < 4; ++ql) {
        float z1 = acc1[ql] * s1[lane] + o1[lane];
        z1 = fmaxf(z1, 0.0f);
        h1s[wv][ql][lane] = z1;
    }
    __syncthreads();

    float a2[4];
#pragma unroll
    for (int ql = 0; ql < 4; ++ql) a2[ql] = b1f[lane];
    {
        const float4* wr2 = reinterpret_cast<const float4*>(canon + 28672 + (lane << 6));
#pragma unroll
        for (int i = 0; i < 16; ++i) {
            float4 w = wr2[i];
#pragma unroll
            for (int ql = 0; ql < 4; ++ql) {
                const float4* hv2 = reinterpret_cast<const float4*>(&h1s[wv][ql][0]);
                float4 a = hv2[i];
                a2[ql] += w.x*a.x + w.y*a.y + w.z*a.z + w.w*a.w;
            }
        }
    }
#pragma unroll
    for (int ql = 0; ql < 4; ++ql) {
        size_t ob = ((size_t)(qbase + ql) << 6) + lane;
        if (f32) ((float*)outp)[ob] = a2[ql];
        else     ((u16*)outp)[ob]   = f2bf(a2[ql]);
    }
}

extern "C" void kernel_launch(void* const* d_in, const int* in_sizes, int n_in,
                              void* d_out, int out_size, void* d_ws, size_t ws_size,
                              hipStream_t stream) {
    const void* pcl   = d_in[0];
    const void* noise = d_in[1];
    const void* feat  = d_in[2];
    const void* w2a   = d_in[3];
    const void* b2a   = d_in[4];
    const void* g2a   = d_in[5];
    const void* bt2a  = d_in[6];
    const void* w2b   = d_in[7];
    const void* b2b   = d_in[8];
    const void* w1a   = d_in[9];
    const void* b1a   = d_in[10];
    const void* g1a   = d_in[11];
    const void* bt1a  = d_in[12];
    const void* w1b   = d_in[13];
    const void* b1b   = d_in[14];

    char* ws = (char*)d_ws;
    float4* pcl4 = (float4*)ws;                    // 128 KB: [B,M] x (x,y,z,sumsq)
    u16* cidx = (u16*)(ws + 131072);               // 32 KB: [B,N]
    u16* knn  = (u16*)(ws + 163840);               // 256 KB: [B,M,16]
    float* canon = (float*)(ws + 425984);          // 128 KB: fp32 w2b|w1a|w1b
    // total workspace: 557,056 bytes

    k_canon<<<128,  256, 0, stream>>>(noise, w2b, w1a, w1b, canon);
    k_prep <<<32,   256, 0, stream>>>(noise, pcl, pcl4);
    k_close<<<1024, 256, 0, stream>>>(pcl4, noise, cidx);
    k_knnh <<<8192, 256, 0, stream>>>(pcl4, knn);
    k_tail <<<1024, 256, 0, stream>>>(pcl4, noise, feat, cidx, knn,
                                      w2a, b2a, g2a, bt2a, canon, b2b,
                                      b1a, g1a, bt1a, b1b, d_out);
}